// Round 10
// baseline (403.310 us; speedup 1.0000x reference)
//
#include <hip/hip_runtime.h>
#include <math.h>

#define NEG_SLOPE 0.2f

typedef int   v4i __attribute__((ext_vector_type(4)));
typedef float v4f __attribute__((ext_vector_type(4)));

static __device__ __forceinline__ float leaky(float v){ return v > 0.f ? v : NEG_SLOPE * v; }
static __device__ __forceinline__ float eluf(float v){ return v > 0.f ? v : expm1f(v); }

// ---------------- CSR build (XCD-range-partitioned) ----------------
__global__ void __launch_bounds__(256) hist_k(const int* __restrict__ edst, int* __restrict__ deg,
                                              int Eg, int Etot, int N){
  const int slot = blockIdx.x & 7;
  const int lo = (int)(((long long)slot * N) >> 3);
  const int hi = (int)(((long long)(slot + 1) * N) >> 3);
  const int stride = (gridDim.x >> 3) * blockDim.x;
  for (int e = (blockIdx.x >> 3) * blockDim.x + threadIdx.x; e < Etot; e += stride){
    int d = (e < Eg) ? __builtin_nontemporal_load(&edst[e]) : (e - Eg);
    if (d >= lo && d < hi) atomicAdd(&deg[d], 1);
  }
}

__global__ void __launch_bounds__(256) scatter_k(const int* __restrict__ esrc, const int* __restrict__ edst,
                                                 int* __restrict__ cursor, int* __restrict__ csr_src,
                                                 int Eg, int Etot, int N){
  const int slot = blockIdx.x & 7;
  const int lo = (int)(((long long)slot * N) >> 3);
  const int hi = (int)(((long long)(slot + 1) * N) >> 3);
  const int stride = (gridDim.x >> 3) * blockDim.x;
  for (int e = (blockIdx.x >> 3) * blockDim.x + threadIdx.x; e < Etot; e += stride){
    int s, d;
    if (e < Eg){
      d = __builtin_nontemporal_load(&edst[e]);
      if (d < lo || d >= hi) continue;
      s = __builtin_nontemporal_load(&esrc[e]);
    } else { s = d = e - Eg; if (d < lo || d >= hi) continue; }
    int pos = atomicAdd(&cursor[d], 1);
    __builtin_nontemporal_store(s, &csr_src[pos]);
  }
}

// A: per-block sums (2048 elems / 256-thread block)
__global__ void __launch_bounds__(256) scan_part_k(const int* __restrict__ deg,
                                                   int* __restrict__ bsum, int N){
  __shared__ int red[256];
  const int t = threadIdx.x;
  const int base = blockIdx.x * 2048;
  int sum = 0;
  #pragma unroll
  for (int i = 0; i < 8; ++i){
    int idx = base + t + i * 256;
    if (idx < N) sum += deg[idx];
  }
  red[t] = sum; __syncthreads();
  #pragma unroll
  for (int d = 128; d; d >>= 1){
    if (t < d) red[t] += red[t + d];
    __syncthreads();
  }
  if (t == 0) bsum[blockIdx.x] = red[0];
}

// B: one wave scans the block sums (nb <= 64)
__global__ void scan_tops_k(const int* __restrict__ bsum, int* __restrict__ boff,
                            int* __restrict__ row, int nb, int N){
  int t = threadIdx.x;
  int v = (t < nb) ? bsum[t] : 0;
  int orig = v;
  #pragma unroll
  for (int off = 1; off < 64; off <<= 1){
    int u = __shfl_up(v, off, 64);
    if (t >= off) v += u;
  }
  if (t < nb) boff[t] = v - orig;
  if (t == nb - 1) row[N] = v;
}

// C: per-block local exclusive scan + global offset, write row & cursor
__global__ void __launch_bounds__(256) scan_write_k(const int* __restrict__ deg,
                                                    const int* __restrict__ boff,
                                                    int* __restrict__ row, int* __restrict__ cursor, int N){
  __shared__ int sdeg[2048];
  __shared__ int tsum[256];
  const int t = threadIdx.x;
  const int base = blockIdx.x * 2048;
  for (int i = t; i < 2048; i += 256){
    int idx = base + i;
    sdeg[i] = (idx < N) ? deg[idx] : 0;
  }
  __syncthreads();
  const int off = t * 8;
  int sum = 0;
  #pragma unroll
  for (int i = 0; i < 8; ++i) sum += sdeg[off + i];
  tsum[t] = sum; __syncthreads();
  for (int d = 1; d < 256; d <<= 1){
    int v = (t >= d) ? tsum[t - d] : 0;
    __syncthreads();
    tsum[t] += v;
    __syncthreads();
  }
  int run = boff[blockIdx.x] + ((t == 0) ? 0 : tsum[t - 1]);
  #pragma unroll
  for (int i = 0; i < 8; ++i){
    int idx = base + off + i;
    if (idx < N){ row[idx] = run; cursor[idx] = run; run += sdeg[off + i]; }
  }
}

// ---------------- layer 1 (Fin = 1, rank-1) ----------------
__global__ void dots1_k(const float* __restrict__ W1, const float* __restrict__ a_s,
                        const float* __restrict__ a_d, float* __restrict__ dAdD){
  int t = threadIdx.x;
  float ps = W1[t] * a_s[t];
  float pd = W1[t] * a_d[t];
  #pragma unroll
  for (int off = 16; off; off >>= 1){
    ps += __shfl_xor(ps, off, 32);
    pd += __shfl_xor(pd, off, 32);
  }
  if ((t & 31) == 0){ dAdD[t >> 5] = ps; dAdD[4 + (t >> 5)] = pd; }
}

// layer-1 softmax scalars only: r4[n] = (t_h/s_h for h=0..3). 8 lanes/node.
__global__ void __launch_bounds__(256) r1_k(const int* __restrict__ row, const int* __restrict__ csr_src,
                                            const float* __restrict__ x, const float* __restrict__ dAdD,
                                            float4* __restrict__ r4, int N){
  int node = blockIdx.x * 32 + (threadIdx.x >> 3);
  if (node >= N) return;
  const int q = threadIdx.x & 7;
  const int start = row[node], end = row[node + 1];
  const float xd = x[node];
  float dA0 = dAdD[0], dA1 = dAdD[1], dA2 = dAdD[2], dA3 = dAdD[3];
  float e0d = xd * dAdD[4], e1d = xd * dAdD[5], e2d = xd * dAdD[6], e3d = xd * dAdD[7];

  float s0 = 0.f, s1 = 0.f, s2 = 0.f, s3 = 0.f;
  float t0 = 0.f, t1 = 0.f, t2 = 0.f, t3 = 0.f;
  for (int i = start + q; i < end; i += 8){
    float xs = x[__builtin_nontemporal_load(&csr_src[i])];
    float p0 = __expf(leaky(xs * dA0 + e0d));
    float p1 = __expf(leaky(xs * dA1 + e1d));
    float p2 = __expf(leaky(xs * dA2 + e2d));
    float p3 = __expf(leaky(xs * dA3 + e3d));
    s0 += p0; s1 += p1; s2 += p2; s3 += p3;
    t0 += p0 * xs; t1 += p1 * xs; t2 += p2 * xs; t3 += p3 * xs;
  }
  #pragma unroll
  for (int off = 4; off; off >>= 1){
    s0 += __shfl_xor(s0, off, 8); t0 += __shfl_xor(t0, off, 8);
    s1 += __shfl_xor(s1, off, 8); t1 += __shfl_xor(t1, off, 8);
    s2 += __shfl_xor(s2, off, 8); t2 += __shfl_xor(t2, off, 8);
    s3 += __shfl_xor(s3, off, 8); t3 += __shfl_xor(t3, off, 8);
  }
  if (q == 0) r4[node] = make_float4(t0 / s0, t1 / s1, t2 / s2, t3 / s3);
}

// ---------------- layer 2 dense: h = act1(Nx128) * W(128x128) ----------------
// act1 reconstructed in LDS from r4 + W1 + b1 (rank-1 per head + ELU).
// as_/ad_ outputs head-major [4][N].
__global__ void __launch_bounds__(256) gemm2_k(const float4* __restrict__ r4,
                                               const float4* __restrict__ W1_4, const float4* __restrict__ b1_4,
                                               const float* __restrict__ W,
                                               const float* __restrict__ a_s, const float* __restrict__ a_d,
                                               float* __restrict__ h, float* __restrict__ as_, float* __restrict__ ad_,
                                               int N){
  __shared__ float sA[128][68];      // [k][row] act1 tile (34.8 KB)
  __shared__ float sW[2][16][128];   // [buf][k][col]
  const int t = threadIdx.x;
  const int n0 = blockIdx.x * 64;
  const int tx = t & 15, ty = t >> 4;
  const int c0 = tx * 8, r0 = ty * 4;

  const int wk = t >> 5;         // 0..7: W k row
  const int wq = t & 31;         // W col-quad

  float4 rw0, rw1;
  auto gloadW = [&](int k0){
    rw0 = *(const float4*)&W[(size_t)(k0 + wk) * 128 + wq * 4];
    rw1 = *(const float4*)&W[(size_t)(k0 + wk + 8) * 128 + wq * 4];
  };
  auto sstoreW = [&](int buf){
    *(float4*)&sW[buf][wk][wq*4]     = rw0;
    *(float4*)&sW[buf][wk + 8][wq*4] = rw1;
  };

  // stage act1 tile: thread t -> node nl = t>>2, channel group q = t&3 (head q)
  {
    const int nl = t >> 2, q = t & 3;
    const int gn = n0 + nl;
    float r = 0.f;
    bool valid = (gn < N);
    if (valid){
      float4 rv = r4[gn];
      r = (q == 0) ? rv.x : (q == 1) ? rv.y : (q == 2) ? rv.z : rv.w;
    }
    #pragma unroll
    for (int j = 0; j < 8; ++j){
      float4 w = W1_4[q * 8 + j];
      float4 b = b1_4[q * 8 + j];
      int c = q * 32 + j * 4;
      sA[c + 0][nl] = valid ? eluf(w.x * r + b.x) : 0.f;
      sA[c + 1][nl] = valid ? eluf(w.y * r + b.y) : 0.f;
      sA[c + 2][nl] = valid ? eluf(w.z * r + b.z) : 0.f;
      sA[c + 3][nl] = valid ? eluf(w.w * r + b.w) : 0.f;
    }
  }

  float acc[4][8];
  #pragma unroll
  for (int r = 0; r < 4; ++r)
    #pragma unroll
    for (int c = 0; c < 8; ++c) acc[r][c] = 0.f;

  gloadW(0); sstoreW(0); __syncthreads();

  #pragma unroll 1
  for (int tile = 0; tile < 8; ++tile){
    const int buf = tile & 1;
    if (tile < 7) gloadW((tile + 1) * 16);
    #pragma unroll
    for (int k = 0; k < 16; ++k){
      float4 aa = *(const float4*)&sA[tile * 16 + k][r0];
      float4 w0 = *(const float4*)&sW[buf][k][c0];
      float4 w1 = *(const float4*)&sW[buf][k][c0 + 4];
      float av[4] = {aa.x, aa.y, aa.z, aa.w};
      float wv[8] = {w0.x, w0.y, w0.z, w0.w, w1.x, w1.y, w1.z, w1.w};
      #pragma unroll
      for (int r = 0; r < 4; ++r)
        #pragma unroll
        for (int c = 0; c < 8; ++c) acc[r][c] += av[r] * wv[c];
    }
    if (tile < 7){ sstoreW(1 - buf); __syncthreads(); }
  }

  float asv[8], adv[8];
  #pragma unroll
  for (int c = 0; c < 8; ++c){ asv[c] = a_s[c0 + c]; adv[c] = a_d[c0 + c]; }

  #pragma unroll
  for (int r = 0; r < 4; ++r){
    int n = n0 + r0 + r;
    if (n >= N) continue;
    float4 o0 = make_float4(acc[r][0], acc[r][1], acc[r][2], acc[r][3]);
    float4 o1 = make_float4(acc[r][4], acc[r][5], acc[r][6], acc[r][7]);
    float4* hp = (float4*)&h[(size_t)n * 128 + c0];
    hp[0] = o0; hp[1] = o1;
    float ps = 0.f, pd = 0.f;
    #pragma unroll
    for (int c = 0; c < 8; ++c){ ps += acc[r][c] * asv[c]; pd += acc[r][c] * adv[c]; }
    ps += __shfl_xor(ps, 1); ps += __shfl_xor(ps, 2);
    pd += __shfl_xor(pd, 1); pd += __shfl_xor(pd, 2);
    if ((tx & 3) == 0){
      as_[(size_t)(tx >> 2) * N + n] = ps;   // head-major
      ad_[(size_t)(tx >> 2) * N + n] = pd;
    }
  }
}

// ---------------- per-node aggregate, layer 2: (head, half) XCD-pinned ----------------
// grid.x = cdiv(N,64)*8. slot = blockIdx&7 → XCD; head = slot>>1, half = slot&1.
// Per-XCD h footprint = N × 64 B = 3.2 MB < 4 MB L2. csr reads nontemporal.
template<bool DO_ELU>
__global__ void __launch_bounds__(256) node_aggr2_k(const int* __restrict__ row, const int* __restrict__ csr_src,
                                                    const float* __restrict__ as_, const float* __restrict__ ad_,
                                                    const float4* __restrict__ h4, const float4* __restrict__ bias4,
                                                    float4* __restrict__ out4, int N){
  const int slot  = blockIdx.x & 7;
  const int chunk = blockIdx.x >> 3;
  const int head  = slot >> 1;
  const int half  = slot & 1;
  const int nl = threadIdx.x >> 2;   // node slot 0..63
  const int q  = threadIdx.x & 3;    // lane within half-head
  const int node = chunk * 64 + nl;
  if (node >= N) return;
  const int start = row[node], end = row[node + 1];
  const float* __restrict__ ash = as_ + (size_t)head * N;
  const float adv = ad_[(size_t)head * N + node];
  const int cix = head * 8 + half * 4 + q;   // float4 index within 32-float4 row

  float s = 0.f;
  float4 acc = make_float4(0.f, 0.f, 0.f, 0.f);
  int i = start;

  int pre = (4 - (start & 3)) & 3;
  if (pre > end - start) pre = end - start;
  for (int k = 0; k < pre; ++k, ++i){
    int src = __builtin_nontemporal_load(&csr_src[i]);
    float p = __expf(leaky(ash[src] + adv));
    float4 hv = h4[(size_t)src*32 + cix];
    s += p;
    acc.x += hv.x*p; acc.y += hv.y*p; acc.z += hv.z*p; acc.w += hv.w*p;
  }
  for (; i + 4 <= end; i += 4){
    v4i ia = __builtin_nontemporal_load((const v4i*)&csr_src[i]);
    float a0 = ash[ia.x], a1 = ash[ia.y], a2 = ash[ia.z], a3 = ash[ia.w];
    float4 h0 = h4[(size_t)ia.x*32 + cix];
    float4 h1 = h4[(size_t)ia.y*32 + cix];
    float4 h2 = h4[(size_t)ia.z*32 + cix];
    float4 h3 = h4[(size_t)ia.w*32 + cix];
    float p0 = __expf(leaky(a0 + adv));
    float p1 = __expf(leaky(a1 + adv));
    float p2 = __expf(leaky(a2 + adv));
    float p3 = __expf(leaky(a3 + adv));
    s += (p0 + p1) + (p2 + p3);
    acc.x += h0.x*p0 + h1.x*p1 + h2.x*p2 + h3.x*p3;
    acc.y += h0.y*p0 + h1.y*p1 + h2.y*p2 + h3.y*p3;
    acc.z += h0.z*p0 + h1.z*p1 + h2.z*p2 + h3.z*p3;
    acc.w += h0.w*p0 + h1.w*p1 + h2.w*p2 + h3.w*p3;
  }
  for (; i < end; ++i){
    int src = __builtin_nontemporal_load(&csr_src[i]);
    float p = __expf(leaky(ash[src] + adv));
    float4 hv = h4[(size_t)src*32 + cix];
    s += p;
    acc.x += hv.x*p; acc.y += hv.y*p; acc.z += hv.z*p; acc.w += hv.w*p;
  }

  float inv = 1.f / s;
  float4 b = bias4[cix];
  float vx = acc.x * inv + b.x;
  float vy = acc.y * inv + b.y;
  float vz = acc.z * inv + b.z;
  float vw = acc.w * inv + b.w;
  if (DO_ELU){
    vx = eluf(vx); vy = eluf(vy); vz = eluf(vz); vw = eluf(vw);
  }
  v4f vv = {vx, vy, vz, vw};
  __builtin_nontemporal_store(vv, (v4f*)&out4[(size_t)node * 32 + cix]);
}

// ---------------- layer 3 ----------------
__global__ void __launch_bounds__(256) transform3_k(const float* __restrict__ A, const float* __restrict__ W3,
                                                    const float* __restrict__ a_s3, const float* __restrict__ a_d3,
                                                    float* __restrict__ h3, float* __restrict__ as_, float* __restrict__ ad_,
                                                    int N){
  int node = blockIdx.x * 8 + (threadIdx.x >> 5);
  if (node >= N) return;
  int j = threadIdx.x & 31;
  float4 a = ((const float4*)A)[(size_t)node * 32 + j];
  float4 w = ((const float4*)W3)[j];
  float acc = a.x * w.x + a.y * w.y + a.z * w.z + a.w * w.w;
  #pragma unroll
  for (int off = 16; off; off >>= 1) acc += __shfl_xor(acc, off, 32);
  if (j == 0){
    h3[node]  = acc;
    as_[node] = acc * a_s3[0];
    ad_[node] = acc * a_d3[0];
  }
}

// 8 lanes per node (avg degree 17)
__global__ void __launch_bounds__(256) node_aggr3_k(const int* __restrict__ row, const int* __restrict__ csr_src,
                                                    const float* __restrict__ as_, const float* __restrict__ ad_,
                                                    const float* __restrict__ h3, const float* __restrict__ b3,
                                                    float* __restrict__ out, int N){
  int node = blockIdx.x * 32 + (threadIdx.x >> 3);
  if (node >= N) return;
  int q = threadIdx.x & 7;
  int start = row[node], end = row[node + 1];
  float adv = ad_[node];
  float s = 0.f, acc = 0.f;
  for (int i = start + q; i < end; i += 8){
    int src = __builtin_nontemporal_load(&csr_src[i]);
    float p = __expf(leaky(as_[src] + adv));
    s += p; acc += h3[src] * p;
  }
  #pragma unroll
  for (int off = 4; off; off >>= 1){
    s += __shfl_xor(s, off, 8);
    acc += __shfl_xor(acc, off, 8);
  }
  if (q == 0) out[node] = acc / s + b3[0];
}

// ---------------- launch ----------------
extern "C" void kernel_launch(void* const* d_in, const int* in_sizes, int n_in,
                              void* d_out, int out_size, void* d_ws, size_t ws_size,
                              hipStream_t stream){
  const float* x   = (const float*)d_in[0];
  const int*   ei  = (const int*)  d_in[1];
  const float* W1  = (const float*)d_in[2];
  const float* as1 = (const float*)d_in[3];
  const float* ad1 = (const float*)d_in[4];
  const float* b1  = (const float*)d_in[5];
  const float* W2  = (const float*)d_in[6];
  const float* as2 = (const float*)d_in[7];
  const float* ad2 = (const float*)d_in[8];
  const float* b2  = (const float*)d_in[9];
  const float* W3  = (const float*)d_in[10];
  const float* as3 = (const float*)d_in[11];
  const float* ad3 = (const float*)d_in[12];
  const float* b3  = (const float*)d_in[13];

  const int N    = in_sizes[0];       // IN_C = 1
  const int Eg   = in_sizes[1] / 2;
  const int Etot = Eg + N;
  const int* esrc = ei;
  const int* edst = ei + Eg;

  char* w = (char*)d_ws;
  auto carve = [&](size_t bytes)->char*{
    char* p = w; w += (bytes + 15) & ~size_t(15); return p;
  };
  float* hbuf   = (float*)carve((size_t)N * 128 * 4);
  float* actA   = (float*)carve((size_t)N * 128 * 4);
  float* r4b    = (float*)carve((size_t)N * 4 * 4);   // r per node per head
  float* asb    = (float*)carve((size_t)N * 4 * 4);   // head-major [4][N]
  float* adb    = (float*)carve((size_t)N * 4 * 4);   // head-major [4][N]
  float* h3b    = (float*)carve((size_t)N * 4);
  float* as3b   = (float*)carve((size_t)N * 4);
  float* ad3b   = (float*)carve((size_t)N * 4);
  int*   deg    = (int*)  carve((size_t)N * 4);
  int*   rowp   = (int*)  carve((size_t)(N + 1) * 4);
  int*   cursor = (int*)  carve((size_t)N * 4);
  int*   csr_src= (int*)  carve((size_t)Etot * 4);
  float* dAdD   = (float*)carve(8 * 4);
  int*   bsum   = (int*)  carve(64 * 4);
  int*   boff   = (int*)  carve(64 * 4);

  const int B = 256;
  auto cdiv = [](int a, int b){ return (a + b - 1) / b; };
  const int nb = cdiv(N, 2048);   // 25 for N=50000 (must be <= 64)

  // ---- CSR build (shared by all 3 layers) ----
  hipMemsetAsync(deg, 0, (size_t)N * 4, stream);
  hist_k<<<128 * 8, B, 0, stream>>>(edst, deg, Eg, Etot, N);
  scan_part_k<<<nb, B, 0, stream>>>(deg, bsum, N);
  scan_tops_k<<<1, 64, 0, stream>>>(bsum, boff, rowp, nb, N);
  scan_write_k<<<nb, B, 0, stream>>>(deg, boff, rowp, cursor, N);
  scatter_k<<<128 * 8, B, 0, stream>>>(esrc, edst, cursor, csr_src, Eg, Etot, N);

  // ---- layer 1 (rank-1: only softmax scalars r) ----
  dots1_k<<<1, 128, 0, stream>>>(W1, as1, ad1, dAdD);
  r1_k<<<cdiv(N, 32), B, 0, stream>>>(rowp, csr_src, x, dAdD, (float4*)r4b, N);

  // ---- layer 2 (act1 reconstructed in LDS) ----
  gemm2_k<<<cdiv(N, 64), B, 0, stream>>>((const float4*)r4b, (const float4*)W1, (const float4*)b1,
                                         W2, as2, ad2, hbuf, asb, adb, N);
  node_aggr2_k<true><<<cdiv(N, 64) * 8, B, 0, stream>>>(rowp, csr_src, asb, adb,
                                                        (const float4*)hbuf, (const float4*)b2,
                                                        (float4*)actA, N);

  // ---- layer 3 (H=1, C=1) ----
  transform3_k<<<cdiv(N, 8), B, 0, stream>>>(actA, W3, as3, ad3, h3b, as3b, ad3b, N);
  node_aggr3_k<<<cdiv(N, 32), B, 0, stream>>>(rowp, csr_src, as3b, ad3b, h3b, b3, (float*)d_out, N);
}

// Round 11
// 303.328 us; speedup vs baseline: 1.3296x; 1.3296x over previous
//
#include <hip/hip_runtime.h>
#include <math.h>

#define NEG_SLOPE 0.2f

static __device__ __forceinline__ float leaky(float v){ return v > 0.f ? v : NEG_SLOPE * v; }
static __device__ __forceinline__ float eluf(float v){ return v > 0.f ? v : expm1f(v); }

// ---------------- CSR build (XCD-range-partitioned) ----------------
__global__ void __launch_bounds__(256) hist_k(const int* __restrict__ edst, int* __restrict__ deg,
                                              int Eg, int Etot, int N){
  const int slot = blockIdx.x & 7;
  const int lo = (int)(((long long)slot * N) >> 3);
  const int hi = (int)(((long long)(slot + 1) * N) >> 3);
  const int stride = (gridDim.x >> 3) * blockDim.x;
  for (int e = (blockIdx.x >> 3) * blockDim.x + threadIdx.x; e < Etot; e += stride){
    int d = (e < Eg) ? edst[e] : (e - Eg);
    if (d >= lo && d < hi) atomicAdd(&deg[d], 1);
  }
}

__global__ void __launch_bounds__(256) scatter_k(const int* __restrict__ esrc, const int* __restrict__ edst,
                                                 int* __restrict__ cursor, int* __restrict__ csr_src,
                                                 int Eg, int Etot, int N){
  const int slot = blockIdx.x & 7;
  const int lo = (int)(((long long)slot * N) >> 3);
  const int hi = (int)(((long long)(slot + 1) * N) >> 3);
  const int stride = (gridDim.x >> 3) * blockDim.x;
  for (int e = (blockIdx.x >> 3) * blockDim.x + threadIdx.x; e < Etot; e += stride){
    int s, d;
    if (e < Eg){ d = edst[e]; if (d < lo || d >= hi) continue; s = esrc[e]; }
    else { s = d = e - Eg; if (d < lo || d >= hi) continue; }
    int pos = atomicAdd(&cursor[d], 1);
    csr_src[pos] = s;
  }
}

// A: per-block sums (2048 elems / 256-thread block)
__global__ void __launch_bounds__(256) scan_part_k(const int* __restrict__ deg,
                                                   int* __restrict__ bsum, int N){
  __shared__ int red[256];
  const int t = threadIdx.x;
  const int base = blockIdx.x * 2048;
  int sum = 0;
  #pragma unroll
  for (int i = 0; i < 8; ++i){
    int idx = base + t + i * 256;
    if (idx < N) sum += deg[idx];
  }
  red[t] = sum; __syncthreads();
  #pragma unroll
  for (int d = 128; d; d >>= 1){
    if (t < d) red[t] += red[t + d];
    __syncthreads();
  }
  if (t == 0) bsum[blockIdx.x] = red[0];
}

// B: one wave scans the block sums (nb <= 64)
__global__ void scan_tops_k(const int* __restrict__ bsum, int* __restrict__ boff,
                            int* __restrict__ row, int nb, int N){
  int t = threadIdx.x;
  int v = (t < nb) ? bsum[t] : 0;
  int orig = v;
  #pragma unroll
  for (int off = 1; off < 64; off <<= 1){
    int u = __shfl_up(v, off, 64);
    if (t >= off) v += u;
  }
  if (t < nb) boff[t] = v - orig;
  if (t == nb - 1) row[N] = v;
}

// C: per-block local exclusive scan + global offset, write row & cursor
__global__ void __launch_bounds__(256) scan_write_k(const int* __restrict__ deg,
                                                    const int* __restrict__ boff,
                                                    int* __restrict__ row, int* __restrict__ cursor, int N){
  __shared__ int sdeg[2048];
  __shared__ int tsum[256];
  const int t = threadIdx.x;
  const int base = blockIdx.x * 2048;
  for (int i = t; i < 2048; i += 256){
    int idx = base + i;
    sdeg[i] = (idx < N) ? deg[idx] : 0;
  }
  __syncthreads();
  const int off = t * 8;
  int sum = 0;
  #pragma unroll
  for (int i = 0; i < 8; ++i) sum += sdeg[off + i];
  tsum[t] = sum; __syncthreads();
  for (int d = 1; d < 256; d <<= 1){
    int v = (t >= d) ? tsum[t - d] : 0;
    __syncthreads();
    tsum[t] += v;
    __syncthreads();
  }
  int run = boff[blockIdx.x] + ((t == 0) ? 0 : tsum[t - 1]);
  #pragma unroll
  for (int i = 0; i < 8; ++i){
    int idx = base + off + i;
    if (idx < N){ row[idx] = run; cursor[idx] = run; run += sdeg[off + i]; }
  }
}

// ---------------- layer 1 (Fin = 1, rank-1) ----------------
__global__ void dots1_k(const float* __restrict__ W1, const float* __restrict__ a_s,
                        const float* __restrict__ a_d, float* __restrict__ dAdD){
  int t = threadIdx.x;
  float ps = W1[t] * a_s[t];
  float pd = W1[t] * a_d[t];
  #pragma unroll
  for (int off = 16; off; off >>= 1){
    ps += __shfl_xor(ps, off, 32);
    pd += __shfl_xor(pd, off, 32);
  }
  if ((t & 31) == 0){ dAdD[t >> 5] = ps; dAdD[4 + (t >> 5)] = pd; }
}

// layer-1 softmax scalars only: r4[n] = (t_h/s_h for h=0..3). 8 lanes/node.
__global__ void __launch_bounds__(256) r1_k(const int* __restrict__ row, const int* __restrict__ csr_src,
                                            const float* __restrict__ x, const float* __restrict__ dAdD,
                                            float4* __restrict__ r4, int N){
  int node = blockIdx.x * 32 + (threadIdx.x >> 3);
  if (node >= N) return;
  const int q = threadIdx.x & 7;
  const int start = row[node], end = row[node + 1];
  const float xd = x[node];
  float dA0 = dAdD[0], dA1 = dAdD[1], dA2 = dAdD[2], dA3 = dAdD[3];
  float e0d = xd * dAdD[4], e1d = xd * dAdD[5], e2d = xd * dAdD[6], e3d = xd * dAdD[7];

  float s0 = 0.f, s1 = 0.f, s2 = 0.f, s3 = 0.f;
  float t0 = 0.f, t1 = 0.f, t2 = 0.f, t3 = 0.f;
  for (int i = start + q; i < end; i += 8){
    float xs = x[csr_src[i]];
    float p0 = __expf(leaky(xs * dA0 + e0d));
    float p1 = __expf(leaky(xs * dA1 + e1d));
    float p2 = __expf(leaky(xs * dA2 + e2d));
    float p3 = __expf(leaky(xs * dA3 + e3d));
    s0 += p0; s1 += p1; s2 += p2; s3 += p3;
    t0 += p0 * xs; t1 += p1 * xs; t2 += p2 * xs; t3 += p3 * xs;
  }
  #pragma unroll
  for (int off = 4; off; off >>= 1){
    s0 += __shfl_xor(s0, off, 8); t0 += __shfl_xor(t0, off, 8);
    s1 += __shfl_xor(s1, off, 8); t1 += __shfl_xor(t1, off, 8);
    s2 += __shfl_xor(s2, off, 8); t2 += __shfl_xor(t2, off, 8);
    s3 += __shfl_xor(s3, off, 8); t3 += __shfl_xor(t3, off, 8);
  }
  if (q == 0) r4[node] = make_float4(t0 / s0, t1 / s1, t2 / s2, t3 / s3);
}

// ---------------- layer 2 dense: h = act1(Nx128) * W(128x128) ----------------
// act1 reconstructed in LDS from r4 + W1 + b1 (rank-1 per head + ELU).
// as_/ad_ outputs head-major [4][N].
__global__ void __launch_bounds__(256) gemm2_k(const float4* __restrict__ r4,
                                               const float4* __restrict__ W1_4, const float4* __restrict__ b1_4,
                                               const float* __restrict__ W,
                                               const float* __restrict__ a_s, const float* __restrict__ a_d,
                                               float* __restrict__ h, float* __restrict__ as_, float* __restrict__ ad_,
                                               int N){
  __shared__ float sA[128][68];      // [k][row] act1 tile (34.8 KB)
  __shared__ float sW[2][16][128];   // [buf][k][col]
  const int t = threadIdx.x;
  const int n0 = blockIdx.x * 64;
  const int tx = t & 15, ty = t >> 4;
  const int c0 = tx * 8, r0 = ty * 4;

  const int wk = t >> 5;         // 0..7: W k row
  const int wq = t & 31;         // W col-quad

  float4 rw0, rw1;
  auto gloadW = [&](int k0){
    rw0 = *(const float4*)&W[(size_t)(k0 + wk) * 128 + wq * 4];
    rw1 = *(const float4*)&W[(size_t)(k0 + wk + 8) * 128 + wq * 4];
  };
  auto sstoreW = [&](int buf){
    *(float4*)&sW[buf][wk][wq*4]     = rw0;
    *(float4*)&sW[buf][wk + 8][wq*4] = rw1;
  };

  // stage act1 tile: thread t -> node nl = t>>2, head q = t&3
  {
    const int nl = t >> 2, q = t & 3;
    const int gn = n0 + nl;
    float r = 0.f;
    bool valid = (gn < N);
    if (valid){
      float4 rv = r4[gn];
      r = (q == 0) ? rv.x : (q == 1) ? rv.y : (q == 2) ? rv.z : rv.w;
    }
    #pragma unroll
    for (int j = 0; j < 8; ++j){
      float4 w = W1_4[q * 8 + j];
      float4 b = b1_4[q * 8 + j];
      int c = q * 32 + j * 4;
      sA[c + 0][nl] = valid ? eluf(w.x * r + b.x) : 0.f;
      sA[c + 1][nl] = valid ? eluf(w.y * r + b.y) : 0.f;
      sA[c + 2][nl] = valid ? eluf(w.z * r + b.z) : 0.f;
      sA[c + 3][nl] = valid ? eluf(w.w * r + b.w) : 0.f;
    }
  }

  float acc[4][8];
  #pragma unroll
  for (int r = 0; r < 4; ++r)
    #pragma unroll
    for (int c = 0; c < 8; ++c) acc[r][c] = 0.f;

  gloadW(0); sstoreW(0); __syncthreads();

  #pragma unroll 1
  for (int tile = 0; tile < 8; ++tile){
    const int buf = tile & 1;
    if (tile < 7) gloadW((tile + 1) * 16);
    #pragma unroll
    for (int k = 0; k < 16; ++k){
      float4 aa = *(const float4*)&sA[tile * 16 + k][r0];
      float4 w0 = *(const float4*)&sW[buf][k][c0];
      float4 w1 = *(const float4*)&sW[buf][k][c0 + 4];
      float av[4] = {aa.x, aa.y, aa.z, aa.w};
      float wv[8] = {w0.x, w0.y, w0.z, w0.w, w1.x, w1.y, w1.z, w1.w};
      #pragma unroll
      for (int r = 0; r < 4; ++r)
        #pragma unroll
        for (int c = 0; c < 8; ++c) acc[r][c] += av[r] * wv[c];
    }
    if (tile < 7){ sstoreW(1 - buf); __syncthreads(); }
  }

  float asv[8], adv[8];
  #pragma unroll
  for (int c = 0; c < 8; ++c){ asv[c] = a_s[c0 + c]; adv[c] = a_d[c0 + c]; }

  #pragma unroll
  for (int r = 0; r < 4; ++r){
    int n = n0 + r0 + r;
    if (n >= N) continue;
    float4 o0 = make_float4(acc[r][0], acc[r][1], acc[r][2], acc[r][3]);
    float4 o1 = make_float4(acc[r][4], acc[r][5], acc[r][6], acc[r][7]);
    float4* hp = (float4*)&h[(size_t)n * 128 + c0];
    hp[0] = o0; hp[1] = o1;
    float ps = 0.f, pd = 0.f;
    #pragma unroll
    for (int c = 0; c < 8; ++c){ ps += acc[r][c] * asv[c]; pd += acc[r][c] * adv[c]; }
    ps += __shfl_xor(ps, 1); ps += __shfl_xor(ps, 2);
    pd += __shfl_xor(pd, 1); pd += __shfl_xor(pd, 2);
    if ((tx & 3) == 0){
      as_[(size_t)(tx >> 2) * N + n] = ps;   // head-major
      ad_[(size_t)(tx >> 2) * N + n] = pd;
    }
  }
}

// ---------------- per-node aggregate, layer 2: HEAD-SPLIT + XCD-pinned (R9 form) ----------------
// grid.x = cdiv(N,64)*8. slot = blockIdx&7 → XCD; head = slot>>1, parity = slot&1.
// 8 lanes/node gather the full 128-B head line coalesced.
template<bool DO_ELU>
__global__ void __launch_bounds__(256) node_aggr2_k(const int* __restrict__ row, const int* __restrict__ csr_src,
                                                    const float* __restrict__ as_, const float* __restrict__ ad_,
                                                    const float4* __restrict__ h4, const float4* __restrict__ bias4,
                                                    float4* __restrict__ out4, int N){
  const int slot   = blockIdx.x & 7;
  const int chunk  = blockIdx.x >> 3;
  const int head   = slot >> 1;
  const int parity = slot & 1;
  const int t  = threadIdx.x;
  const int nl = t >> 3;          // node slot 0..31
  const int q  = t & 7;           // lane within head
  const int node = chunk * 64 + parity * 32 + nl;
  if (node >= N) return;
  const int start = row[node], end = row[node + 1];
  const float* __restrict__ ash = as_ + (size_t)head * N;
  const float adv = ad_[(size_t)head * N + node];
  const int cix = head * 8 + q;   // float4 index within a 32-float4 row

  float s = 0.f;
  float4 acc = make_float4(0.f, 0.f, 0.f, 0.f);
  int i = start;

  int pre = (4 - (start & 3)) & 3;
  if (pre > end - start) pre = end - start;
  for (int k = 0; k < pre; ++k, ++i){
    int src = csr_src[i];
    float p = __expf(leaky(ash[src] + adv));
    float4 hv = h4[(size_t)src*32 + cix];
    s += p;
    acc.x += hv.x*p; acc.y += hv.y*p; acc.z += hv.z*p; acc.w += hv.w*p;
  }
  for (; i + 4 <= end; i += 4){
    int4 ia = *(const int4*)&csr_src[i];
    float a0 = ash[ia.x], a1 = ash[ia.y], a2 = ash[ia.z], a3 = ash[ia.w];
    float4 h0 = h4[(size_t)ia.x*32 + cix];
    float4 h1 = h4[(size_t)ia.y*32 + cix];
    float4 h2 = h4[(size_t)ia.z*32 + cix];
    float4 h3 = h4[(size_t)ia.w*32 + cix];
    float p0 = __expf(leaky(a0 + adv));
    float p1 = __expf(leaky(a1 + adv));
    float p2 = __expf(leaky(a2 + adv));
    float p3 = __expf(leaky(a3 + adv));
    s += (p0 + p1) + (p2 + p3);
    acc.x += h0.x*p0 + h1.x*p1 + h2.x*p2 + h3.x*p3;
    acc.y += h0.y*p0 + h1.y*p1 + h2.y*p2 + h3.y*p3;
    acc.z += h0.z*p0 + h1.z*p1 + h2.z*p2 + h3.z*p3;
    acc.w += h0.w*p0 + h1.w*p1 + h2.w*p2 + h3.w*p3;
  }
  for (; i < end; ++i){
    int src = csr_src[i];
    float p = __expf(leaky(ash[src] + adv));
    float4 hv = h4[(size_t)src*32 + cix];
    s += p;
    acc.x += hv.x*p; acc.y += hv.y*p; acc.z += hv.z*p; acc.w += hv.w*p;
  }

  float inv = 1.f / s;
  float4 b = bias4[cix];
  float4 v;
  v.x = acc.x * inv + b.x;
  v.y = acc.y * inv + b.y;
  v.z = acc.z * inv + b.z;
  v.w = acc.w * inv + b.w;
  if (DO_ELU){
    v.x = eluf(v.x); v.y = eluf(v.y); v.z = eluf(v.z); v.w = eluf(v.w);
  }
  out4[(size_t)node * 32 + cix] = v;
}

// ---------------- layer 3 ----------------
__global__ void __launch_bounds__(256) transform3_k(const float* __restrict__ A, const float* __restrict__ W3,
                                                    const float* __restrict__ a_s3, const float* __restrict__ a_d3,
                                                    float* __restrict__ h3, float* __restrict__ as_, float* __restrict__ ad_,
                                                    int N){
  int node = blockIdx.x * 8 + (threadIdx.x >> 5);
  if (node >= N) return;
  int j = threadIdx.x & 31;
  float4 a = ((const float4*)A)[(size_t)node * 32 + j];
  float4 w = ((const float4*)W3)[j];
  float acc = a.x * w.x + a.y * w.y + a.z * w.z + a.w * w.w;
  #pragma unroll
  for (int off = 16; off; off >>= 1) acc += __shfl_xor(acc, off, 32);
  if (j == 0){
    h3[node]  = acc;
    as_[node] = acc * a_s3[0];
    ad_[node] = acc * a_d3[0];
  }
}

// 8 lanes per node (avg degree 17)
__global__ void __launch_bounds__(256) node_aggr3_k(const int* __restrict__ row, const int* __restrict__ csr_src,
                                                    const float* __restrict__ as_, const float* __restrict__ ad_,
                                                    const float* __restrict__ h3, const float* __restrict__ b3,
                                                    float* __restrict__ out, int N){
  int node = blockIdx.x * 32 + (threadIdx.x >> 3);
  if (node >= N) return;
  int q = threadIdx.x & 7;
  int start = row[node], end = row[node + 1];
  float adv = ad_[node];
  float s = 0.f, acc = 0.f;
  for (int i = start + q; i < end; i += 8){
    int src = csr_src[i];
    float p = __expf(leaky(as_[src] + adv));
    s += p; acc += h3[src] * p;
  }
  #pragma unroll
  for (int off = 4; off; off >>= 1){
    s += __shfl_xor(s, off, 8);
    acc += __shfl_xor(acc, off, 8);
  }
  if (q == 0) out[node] = acc / s + b3[0];
}

// ---------------- launch ----------------
extern "C" void kernel_launch(void* const* d_in, const int* in_sizes, int n_in,
                              void* d_out, int out_size, void* d_ws, size_t ws_size,
                              hipStream_t stream){
  const float* x   = (const float*)d_in[0];
  const int*   ei  = (const int*)  d_in[1];
  const float* W1  = (const float*)d_in[2];
  const float* as1 = (const float*)d_in[3];
  const float* ad1 = (const float*)d_in[4];
  const float* b1  = (const float*)d_in[5];
  const float* W2  = (const float*)d_in[6];
  const float* as2 = (const float*)d_in[7];
  const float* ad2 = (const float*)d_in[8];
  const float* b2  = (const float*)d_in[9];
  const float* W3  = (const float*)d_in[10];
  const float* as3 = (const float*)d_in[11];
  const float* ad3 = (const float*)d_in[12];
  const float* b3  = (const float*)d_in[13];

  const int N    = in_sizes[0];       // IN_C = 1
  const int Eg   = in_sizes[1] / 2;
  const int Etot = Eg + N;
  const int* esrc = ei;
  const int* edst = ei + Eg;

  char* w = (char*)d_ws;
  auto carve = [&](size_t bytes)->char*{
    char* p = w; w += (bytes + 15) & ~size_t(15); return p;
  };
  float* hbuf   = (float*)carve((size_t)N * 128 * 4);
  float* actA   = (float*)carve((size_t)N * 128 * 4);
  float* r4b    = (float*)carve((size_t)N * 4 * 4);   // r per node per head
  float* asb    = (float*)carve((size_t)N * 4 * 4);   // head-major [4][N]
  float* adb    = (float*)carve((size_t)N * 4 * 4);   // head-major [4][N]
  float* h3b    = (float*)carve((size_t)N * 4);
  float* as3b   = (float*)carve((size_t)N * 4);
  float* ad3b   = (float*)carve((size_t)N * 4);
  int*   deg    = (int*)  carve((size_t)N * 4);
  int*   rowp   = (int*)  carve((size_t)(N + 1) * 4);
  int*   cursor = (int*)  carve((size_t)N * 4);
  int*   csr_src= (int*)  carve((size_t)Etot * 4);
  float* dAdD   = (float*)carve(8 * 4);
  int*   bsum   = (int*)  carve(64 * 4);
  int*   boff   = (int*)  carve(64 * 4);

  const int B = 256;
  auto cdiv = [](int a, int b){ return (a + b - 1) / b; };
  const int nb = cdiv(N, 2048);   // 25 for N=50000 (must be <= 64)

  // ---- CSR build (shared by all 3 layers) ----
  hipMemsetAsync(deg, 0, (size_t)N * 4, stream);
  hist_k<<<128 * 8, B, 0, stream>>>(edst, deg, Eg, Etot, N);
  scan_part_k<<<nb, B, 0, stream>>>(deg, bsum, N);
  scan_tops_k<<<1, 64, 0, stream>>>(bsum, boff, rowp, nb, N);
  scan_write_k<<<nb, B, 0, stream>>>(deg, boff, rowp, cursor, N);
  scatter_k<<<128 * 8, B, 0, stream>>>(esrc, edst, cursor, csr_src, Eg, Etot, N);

  // ---- layer 1 (rank-1: only softmax scalars r) ----
  dots1_k<<<1, 128, 0, stream>>>(W1, as1, ad1, dAdD);
  r1_k<<<cdiv(N, 32), B, 0, stream>>>(rowp, csr_src, x, dAdD, (float4*)r4b, N);

  // ---- layer 2 (act1 reconstructed in LDS) ----
  gemm2_k<<<cdiv(N, 64), B, 0, stream>>>((const float4*)r4b, (const float4*)W1, (const float4*)b1,
                                         W2, as2, ad2, hbuf, asb, adb, N);
  node_aggr2_k<true><<<cdiv(N, 64) * 8, B, 0, stream>>>(rowp, csr_src, asb, adb,
                                                        (const float4*)hbuf, (const float4*)b2,
                                                        (float4*)actA, N);

  // ---- layer 3 (H=1, C=1) ----
  transform3_k<<<cdiv(N, 8), B, 0, stream>>>(actA, W3, as3, ad3, h3b, as3b, ad3b, N);
  node_aggr3_k<<<cdiv(N, 32), B, 0, stream>>>(rowp, csr_src, as3b, ad3b, h3b, b3, (float*)d_out, N);
}

// Round 12
// 292.093 us; speedup vs baseline: 1.3808x; 1.0385x over previous
//
#include <hip/hip_runtime.h>
#include <math.h>

#define NEG_SLOPE 0.2f

typedef _Float16 hv4 __attribute__((ext_vector_type(4)));
typedef _Float16 hv8 __attribute__((ext_vector_type(8)));

static __device__ __forceinline__ float leaky(float v){ return v > 0.f ? v : NEG_SLOPE * v; }
static __device__ __forceinline__ float eluf(float v){ return v > 0.f ? v : expm1f(v); }

// ---------------- CSR build (XCD-range-partitioned) ----------------
__global__ void __launch_bounds__(256) hist_k(const int* __restrict__ edst, int* __restrict__ deg,
                                              int Eg, int Etot, int N){
  const int slot = blockIdx.x & 7;
  const int lo = (int)(((long long)slot * N) >> 3);
  const int hi = (int)(((long long)(slot + 1) * N) >> 3);
  const int stride = (gridDim.x >> 3) * blockDim.x;
  for (int e = (blockIdx.x >> 3) * blockDim.x + threadIdx.x; e < Etot; e += stride){
    int d = (e < Eg) ? edst[e] : (e - Eg);
    if (d >= lo && d < hi) atomicAdd(&deg[d], 1);
  }
}

__global__ void __launch_bounds__(256) scatter_k(const int* __restrict__ esrc, const int* __restrict__ edst,
                                                 int* __restrict__ cursor, int* __restrict__ csr_src,
                                                 int Eg, int Etot, int N){
  const int slot = blockIdx.x & 7;
  const int lo = (int)(((long long)slot * N) >> 3);
  const int hi = (int)(((long long)(slot + 1) * N) >> 3);
  const int stride = (gridDim.x >> 3) * blockDim.x;
  for (int e = (blockIdx.x >> 3) * blockDim.x + threadIdx.x; e < Etot; e += stride){
    int s, d;
    if (e < Eg){ d = edst[e]; if (d < lo || d >= hi) continue; s = esrc[e]; }
    else { s = d = e - Eg; if (d < lo || d >= hi) continue; }
    int pos = atomicAdd(&cursor[d], 1);
    csr_src[pos] = s;
  }
}

// A: per-block sums (2048 elems / 256-thread block)
__global__ void __launch_bounds__(256) scan_part_k(const int* __restrict__ deg,
                                                   int* __restrict__ bsum, int N){
  __shared__ int red[256];
  const int t = threadIdx.x;
  const int base = blockIdx.x * 2048;
  int sum = 0;
  #pragma unroll
  for (int i = 0; i < 8; ++i){
    int idx = base + t + i * 256;
    if (idx < N) sum += deg[idx];
  }
  red[t] = sum; __syncthreads();
  #pragma unroll
  for (int d = 128; d; d >>= 1){
    if (t < d) red[t] += red[t + d];
    __syncthreads();
  }
  if (t == 0) bsum[blockIdx.x] = red[0];
}

// B: one wave scans the block sums (nb <= 64)
__global__ void scan_tops_k(const int* __restrict__ bsum, int* __restrict__ boff,
                            int* __restrict__ row, int nb, int N){
  int t = threadIdx.x;
  int v = (t < nb) ? bsum[t] : 0;
  int orig = v;
  #pragma unroll
  for (int off = 1; off < 64; off <<= 1){
    int u = __shfl_up(v, off, 64);
    if (t >= off) v += u;
  }
  if (t < nb) boff[t] = v - orig;
  if (t == nb - 1) row[N] = v;
}

// C: per-block local exclusive scan + global offset, write row & cursor
__global__ void __launch_bounds__(256) scan_write_k(const int* __restrict__ deg,
                                                    const int* __restrict__ boff,
                                                    int* __restrict__ row, int* __restrict__ cursor, int N){
  __shared__ int sdeg[2048];
  __shared__ int tsum[256];
  const int t = threadIdx.x;
  const int base = blockIdx.x * 2048;
  for (int i = t; i < 2048; i += 256){
    int idx = base + i;
    sdeg[i] = (idx < N) ? deg[idx] : 0;
  }
  __syncthreads();
  const int off = t * 8;
  int sum = 0;
  #pragma unroll
  for (int i = 0; i < 8; ++i) sum += sdeg[off + i];
  tsum[t] = sum; __syncthreads();
  for (int d = 1; d < 256; d <<= 1){
    int v = (t >= d) ? tsum[t - d] : 0;
    __syncthreads();
    tsum[t] += v;
    __syncthreads();
  }
  int run = boff[blockIdx.x] + ((t == 0) ? 0 : tsum[t - 1]);
  #pragma unroll
  for (int i = 0; i < 8; ++i){
    int idx = base + off + i;
    if (idx < N){ row[idx] = run; cursor[idx] = run; run += sdeg[off + i]; }
  }
}

// ---------------- layer 1 (Fin = 1, rank-1) ----------------
__global__ void dots1_k(const float* __restrict__ W1, const float* __restrict__ a_s,
                        const float* __restrict__ a_d, float* __restrict__ dAdD){
  int t = threadIdx.x;
  float ps = W1[t] * a_s[t];
  float pd = W1[t] * a_d[t];
  #pragma unroll
  for (int off = 16; off; off >>= 1){
    ps += __shfl_xor(ps, off, 32);
    pd += __shfl_xor(pd, off, 32);
  }
  if ((t & 31) == 0){ dAdD[t >> 5] = ps; dAdD[4 + (t >> 5)] = pd; }
}

// layer-1 softmax scalars only: r4[n] = (t_h/s_h for h=0..3). 8 lanes/node.
__global__ void __launch_bounds__(256) r1_k(const int* __restrict__ row, const int* __restrict__ csr_src,
                                            const float* __restrict__ x, const float* __restrict__ dAdD,
                                            float4* __restrict__ r4, int N){
  int node = blockIdx.x * 32 + (threadIdx.x >> 3);
  if (node >= N) return;
  const int q = threadIdx.x & 7;
  const int start = row[node], end = row[node + 1];
  const float xd = x[node];
  float dA0 = dAdD[0], dA1 = dAdD[1], dA2 = dAdD[2], dA3 = dAdD[3];
  float e0d = xd * dAdD[4], e1d = xd * dAdD[5], e2d = xd * dAdD[6], e3d = xd * dAdD[7];

  float s0 = 0.f, s1 = 0.f, s2 = 0.f, s3 = 0.f;
  float t0 = 0.f, t1 = 0.f, t2 = 0.f, t3 = 0.f;
  for (int i = start + q; i < end; i += 8){
    float xs = x[csr_src[i]];
    float p0 = __expf(leaky(xs * dA0 + e0d));
    float p1 = __expf(leaky(xs * dA1 + e1d));
    float p2 = __expf(leaky(xs * dA2 + e2d));
    float p3 = __expf(leaky(xs * dA3 + e3d));
    s0 += p0; s1 += p1; s2 += p2; s3 += p3;
    t0 += p0 * xs; t1 += p1 * xs; t2 += p2 * xs; t3 += p3 * xs;
  }
  #pragma unroll
  for (int off = 4; off; off >>= 1){
    s0 += __shfl_xor(s0, off, 8); t0 += __shfl_xor(t0, off, 8);
    s1 += __shfl_xor(s1, off, 8); t1 += __shfl_xor(t1, off, 8);
    s2 += __shfl_xor(s2, off, 8); t2 += __shfl_xor(t2, off, 8);
    s3 += __shfl_xor(s3, off, 8); t3 += __shfl_xor(t3, off, 8);
  }
  if (q == 0) r4[node] = make_float4(t0 / s0, t1 / s1, t2 / s2, t3 / s3);
}

// ---------------- layer 2 dense: h = act1(Nx128) * W(128x128) ----------------
// act1 reconstructed in LDS from r4 + W1 + b1. h written FP16 HEAD-MAJOR [4][N][32].
// as_/ad_ outputs head-major [4][N].
__global__ void __launch_bounds__(256) gemm2_k(const float4* __restrict__ r4,
                                               const float4* __restrict__ W1_4, const float4* __restrict__ b1_4,
                                               const float* __restrict__ W,
                                               const float* __restrict__ a_s, const float* __restrict__ a_d,
                                               _Float16* __restrict__ hh, float* __restrict__ as_, float* __restrict__ ad_,
                                               int N){
  __shared__ float sA[128][68];      // [k][row] act1 tile (34.8 KB)
  __shared__ float sW[2][16][128];   // [buf][k][col]
  const int t = threadIdx.x;
  const int n0 = blockIdx.x * 64;
  const int tx = t & 15, ty = t >> 4;
  const int c0 = tx * 8, r0 = ty * 4;

  const int wk = t >> 5;         // 0..7: W k row
  const int wq = t & 31;         // W col-quad

  float4 rw0, rw1;
  auto gloadW = [&](int k0){
    rw0 = *(const float4*)&W[(size_t)(k0 + wk) * 128 + wq * 4];
    rw1 = *(const float4*)&W[(size_t)(k0 + wk + 8) * 128 + wq * 4];
  };
  auto sstoreW = [&](int buf){
    *(float4*)&sW[buf][wk][wq*4]     = rw0;
    *(float4*)&sW[buf][wk + 8][wq*4] = rw1;
  };

  // stage act1 tile: thread t -> node nl = t>>2, head q = t&3
  {
    const int nl = t >> 2, q = t & 3;
    const int gn = n0 + nl;
    float r = 0.f;
    bool valid = (gn < N);
    if (valid){
      float4 rv = r4[gn];
      r = (q == 0) ? rv.x : (q == 1) ? rv.y : (q == 2) ? rv.z : rv.w;
    }
    #pragma unroll
    for (int j = 0; j < 8; ++j){
      float4 w = W1_4[q * 8 + j];
      float4 b = b1_4[q * 8 + j];
      int c = q * 32 + j * 4;
      sA[c + 0][nl] = valid ? eluf(w.x * r + b.x) : 0.f;
      sA[c + 1][nl] = valid ? eluf(w.y * r + b.y) : 0.f;
      sA[c + 2][nl] = valid ? eluf(w.z * r + b.z) : 0.f;
      sA[c + 3][nl] = valid ? eluf(w.w * r + b.w) : 0.f;
    }
  }

  float acc[4][8];
  #pragma unroll
  for (int r = 0; r < 4; ++r)
    #pragma unroll
    for (int c = 0; c < 8; ++c) acc[r][c] = 0.f;

  gloadW(0); sstoreW(0); __syncthreads();

  #pragma unroll 1
  for (int tile = 0; tile < 8; ++tile){
    const int buf = tile & 1;
    if (tile < 7) gloadW((tile + 1) * 16);
    #pragma unroll
    for (int k = 0; k < 16; ++k){
      float4 aa = *(const float4*)&sA[tile * 16 + k][r0];
      float4 w0 = *(const float4*)&sW[buf][k][c0];
      float4 w1 = *(const float4*)&sW[buf][k][c0 + 4];
      float av[4] = {aa.x, aa.y, aa.z, aa.w};
      float wv[8] = {w0.x, w0.y, w0.z, w0.w, w1.x, w1.y, w1.z, w1.w};
      #pragma unroll
      for (int r = 0; r < 4; ++r)
        #pragma unroll
        for (int c = 0; c < 8; ++c) acc[r][c] += av[r] * wv[c];
    }
    if (tile < 7){ sstoreW(1 - buf); __syncthreads(); }
  }

  float asv[8], adv[8];
  #pragma unroll
  for (int c = 0; c < 8; ++c){ asv[c] = a_s[c0 + c]; adv[c] = a_d[c0 + c]; }

  const int hd  = tx >> 2;            // head of this column group
  const int off = (tx & 3) * 8;       // channel offset within head

  #pragma unroll
  for (int r = 0; r < 4; ++r){
    int n = n0 + r0 + r;
    if (n >= N) continue;
    hv8 hv;
    #pragma unroll
    for (int c = 0; c < 8; ++c) hv[c] = (_Float16)acc[r][c];
    *(hv8*)&hh[((size_t)hd * N + n) * 32 + off] = hv;
    float ps = 0.f, pd = 0.f;
    #pragma unroll
    for (int c = 0; c < 8; ++c){ ps += acc[r][c] * asv[c]; pd += acc[r][c] * adv[c]; }
    ps += __shfl_xor(ps, 1); ps += __shfl_xor(ps, 2);
    pd += __shfl_xor(pd, 1); pd += __shfl_xor(pd, 2);
    if ((tx & 3) == 0){
      as_[(size_t)hd * N + n] = ps;   // head-major
      ad_[(size_t)hd * N + n] = pd;
    }
  }
}

// ---------------- per-node aggregate, layer 2: HEAD-SPLIT + XCD-pinned, fp16 h ----------------
// grid.x = cdiv(N,64)*8. slot = blockIdx&7 → XCD; head = slot>>1, parity = slot&1.
// h is fp16 head-major [4][N][32]: per-XCD footprint 3.2 MB < 4 MB L2, full-line use.
template<bool DO_ELU>
__global__ void __launch_bounds__(256) node_aggr2_k(const int* __restrict__ row, const int* __restrict__ csr_src,
                                                    const float* __restrict__ as_, const float* __restrict__ ad_,
                                                    const _Float16* __restrict__ hh, const float4* __restrict__ bias4,
                                                    float4* __restrict__ out4, int N){
  const int slot   = blockIdx.x & 7;
  const int chunk  = blockIdx.x >> 3;
  const int head   = slot >> 1;
  const int parity = slot & 1;
  const int t  = threadIdx.x;
  const int nl = t >> 3;          // node slot 0..31
  const int q  = t & 7;           // lane within head
  const int node = chunk * 64 + parity * 32 + nl;
  if (node >= N) return;
  const int start = row[node], end = row[node + 1];
  const float* __restrict__ ash = as_ + (size_t)head * N;
  const _Float16* __restrict__ hhh = hh + (size_t)head * N * 32 + q * 4;
  const float adv = ad_[(size_t)head * N + node];

  float s = 0.f;
  float4 acc = make_float4(0.f, 0.f, 0.f, 0.f);
  int i = start;

  int pre = (4 - (start & 3)) & 3;
  if (pre > end - start) pre = end - start;
  for (int k = 0; k < pre; ++k, ++i){
    int src = csr_src[i];
    float p = __expf(leaky(ash[src] + adv));
    hv4 hv = *(const hv4*)&hhh[(size_t)src * 32];
    s += p;
    acc.x += (float)hv.x*p; acc.y += (float)hv.y*p; acc.z += (float)hv.z*p; acc.w += (float)hv.w*p;
  }
  for (; i + 4 <= end; i += 4){
    int4 ia = *(const int4*)&csr_src[i];
    float a0 = ash[ia.x], a1 = ash[ia.y], a2 = ash[ia.z], a3 = ash[ia.w];
    hv4 h0 = *(const hv4*)&hhh[(size_t)ia.x * 32];
    hv4 h1 = *(const hv4*)&hhh[(size_t)ia.y * 32];
    hv4 h2 = *(const hv4*)&hhh[(size_t)ia.z * 32];
    hv4 h3 = *(const hv4*)&hhh[(size_t)ia.w * 32];
    float p0 = __expf(leaky(a0 + adv));
    float p1 = __expf(leaky(a1 + adv));
    float p2 = __expf(leaky(a2 + adv));
    float p3 = __expf(leaky(a3 + adv));
    s += (p0 + p1) + (p2 + p3);
    acc.x += (float)h0.x*p0 + (float)h1.x*p1 + (float)h2.x*p2 + (float)h3.x*p3;
    acc.y += (float)h0.y*p0 + (float)h1.y*p1 + (float)h2.y*p2 + (float)h3.y*p3;
    acc.z += (float)h0.z*p0 + (float)h1.z*p1 + (float)h2.z*p2 + (float)h3.z*p3;
    acc.w += (float)h0.w*p0 + (float)h1.w*p1 + (float)h2.w*p2 + (float)h3.w*p3;
  }
  for (; i < end; ++i){
    int src = csr_src[i];
    float p = __expf(leaky(ash[src] + adv));
    hv4 hv = *(const hv4*)&hhh[(size_t)src * 32];
    s += p;
    acc.x += (float)hv.x*p; acc.y += (float)hv.y*p; acc.z += (float)hv.z*p; acc.w += (float)hv.w*p;
  }

  float inv = 1.f / s;
  const int cix = head * 8 + q;
  float4 b = bias4[cix];
  float4 v;
  v.x = acc.x * inv + b.x;
  v.y = acc.y * inv + b.y;
  v.z = acc.z * inv + b.z;
  v.w = acc.w * inv + b.w;
  if (DO_ELU){
    v.x = eluf(v.x); v.y = eluf(v.y); v.z = eluf(v.z); v.w = eluf(v.w);
  }
  out4[(size_t)node * 32 + cix] = v;
}

// ---------------- layer 3 ----------------
__global__ void __launch_bounds__(256) transform3_k(const float* __restrict__ A, const float* __restrict__ W3,
                                                    const float* __restrict__ a_s3, const float* __restrict__ a_d3,
                                                    float* __restrict__ h3, float* __restrict__ as_, float* __restrict__ ad_,
                                                    int N){
  int node = blockIdx.x * 8 + (threadIdx.x >> 5);
  if (node >= N) return;
  int j = threadIdx.x & 31;
  float4 a = ((const float4*)A)[(size_t)node * 32 + j];
  float4 w = ((const float4*)W3)[j];
  float acc = a.x * w.x + a.y * w.y + a.z * w.z + a.w * w.w;
  #pragma unroll
  for (int off = 16; off; off >>= 1) acc += __shfl_xor(acc, off, 32);
  if (j == 0){
    h3[node]  = acc;
    as_[node] = acc * a_s3[0];
    ad_[node] = acc * a_d3[0];
  }
}

// 8 lanes per node (avg degree 17)
__global__ void __launch_bounds__(256) node_aggr3_k(const int* __restrict__ row, const int* __restrict__ csr_src,
                                                    const float* __restrict__ as_, const float* __restrict__ ad_,
                                                    const float* __restrict__ h3, const float* __restrict__ b3,
                                                    float* __restrict__ out, int N){
  int node = blockIdx.x * 32 + (threadIdx.x >> 3);
  if (node >= N) return;
  int q = threadIdx.x & 7;
  int start = row[node], end = row[node + 1];
  float adv = ad_[node];
  float s = 0.f, acc = 0.f;
  for (int i = start + q; i < end; i += 8){
    int src = csr_src[i];
    float p = __expf(leaky(as_[src] + adv));
    s += p; acc += h3[src] * p;
  }
  #pragma unroll
  for (int off = 4; off; off >>= 1){
    s += __shfl_xor(s, off, 8);
    acc += __shfl_xor(acc, off, 8);
  }
  if (q == 0) out[node] = acc / s + b3[0];
}

// ---------------- launch ----------------
extern "C" void kernel_launch(void* const* d_in, const int* in_sizes, int n_in,
                              void* d_out, int out_size, void* d_ws, size_t ws_size,
                              hipStream_t stream){
  const float* x   = (const float*)d_in[0];
  const int*   ei  = (const int*)  d_in[1];
  const float* W1  = (const float*)d_in[2];
  const float* as1 = (const float*)d_in[3];
  const float* ad1 = (const float*)d_in[4];
  const float* b1  = (const float*)d_in[5];
  const float* W2  = (const float*)d_in[6];
  const float* as2 = (const float*)d_in[7];
  const float* ad2 = (const float*)d_in[8];
  const float* b2  = (const float*)d_in[9];
  const float* W3  = (const float*)d_in[10];
  const float* as3 = (const float*)d_in[11];
  const float* ad3 = (const float*)d_in[12];
  const float* b3  = (const float*)d_in[13];

  const int N    = in_sizes[0];       // IN_C = 1
  const int Eg   = in_sizes[1] / 2;
  const int Etot = Eg + N;
  const int* esrc = ei;
  const int* edst = ei + Eg;

  char* w = (char*)d_ws;
  auto carve = [&](size_t bytes)->char*{
    char* p = w; w += (bytes + 15) & ~size_t(15); return p;
  };
  _Float16* hbuf = (_Float16*)carve((size_t)N * 128 * 2);  // fp16 head-major [4][N][32]
  float* actA   = (float*)carve((size_t)N * 128 * 4);
  float* r4b    = (float*)carve((size_t)N * 4 * 4);
  float* asb    = (float*)carve((size_t)N * 4 * 4);   // head-major [4][N]
  float* adb    = (float*)carve((size_t)N * 4 * 4);   // head-major [4][N]
  float* h3b    = (float*)carve((size_t)N * 4);
  float* as3b   = (float*)carve((size_t)N * 4);
  float* ad3b   = (float*)carve((size_t)N * 4);
  int*   deg    = (int*)  carve((size_t)N * 4);
  int*   rowp   = (int*)  carve((size_t)(N + 1) * 4);
  int*   cursor = (int*)  carve((size_t)N * 4);
  int*   csr_src= (int*)  carve((size_t)Etot * 4);
  float* dAdD   = (float*)carve(8 * 4);
  int*   bsum   = (int*)  carve(64 * 4);
  int*   boff   = (int*)  carve(64 * 4);

  const int B = 256;
  auto cdiv = [](int a, int b){ return (a + b - 1) / b; };
  const int nb = cdiv(N, 2048);   // 25 for N=50000 (must be <= 64)

  // ---- CSR build (shared by all 3 layers) ----
  hipMemsetAsync(deg, 0, (size_t)N * 4, stream);
  hist_k<<<128 * 8, B, 0, stream>>>(edst, deg, Eg, Etot, N);
  scan_part_k<<<nb, B, 0, stream>>>(deg, bsum, N);
  scan_tops_k<<<1, 64, 0, stream>>>(bsum, boff, rowp, nb, N);
  scan_write_k<<<nb, B, 0, stream>>>(deg, boff, rowp, cursor, N);
  scatter_k<<<128 * 8, B, 0, stream>>>(esrc, edst, cursor, csr_src, Eg, Etot, N);

  // ---- layer 1 (rank-1: only softmax scalars r) ----
  dots1_k<<<1, 128, 0, stream>>>(W1, as1, ad1, dAdD);
  r1_k<<<cdiv(N, 32), B, 0, stream>>>(rowp, csr_src, x, dAdD, (float4*)r4b, N);

  // ---- layer 2 (act1 reconstructed in LDS; h fp16 head-major) ----
  gemm2_k<<<cdiv(N, 64), B, 0, stream>>>((const float4*)r4b, (const float4*)W1, (const float4*)b1,
                                         W2, as2, ad2, hbuf, asb, adb, N);
  node_aggr2_k<true><<<cdiv(N, 64) * 8, B, 0, stream>>>(rowp, csr_src, asb, adb,
                                                        hbuf, (const float4*)b2,
                                                        (float4*)actA, N);

  // ---- layer 3 (H=1, C=1) ----
  transform3_k<<<cdiv(N, 8), B, 0, stream>>>(actA, W3, as3, ad3, h3b, as3b, ad3b, N);
  node_aggr3_k<<<cdiv(N, 32), B, 0, stream>>>(rowp, csr_src, as3b, ad3b, h3b, b3, (float*)d_out, N);
}

// Round 13
// 285.964 us; speedup vs baseline: 1.4104x; 1.0214x over previous
//
#include <hip/hip_runtime.h>
#include <math.h>

#define NEG_SLOPE 0.2f

typedef _Float16 hv4 __attribute__((ext_vector_type(4)));
typedef _Float16 hv8 __attribute__((ext_vector_type(8)));

static __device__ __forceinline__ float leaky(float v){ return v > 0.f ? v : NEG_SLOPE * v; }
static __device__ __forceinline__ float eluf(float v){ return v > 0.f ? v : expm1f(v); }
static __device__ __forceinline__ float eluf_fast(float v){ return v > 0.f ? v : __expf(v) - 1.f; }

// ---------------- CSR build (XCD-range-partitioned) ----------------
__global__ void __launch_bounds__(256) hist_k(const int* __restrict__ edst, int* __restrict__ deg,
                                              int Eg, int Etot, int N){
  const int slot = blockIdx.x & 7;
  const int lo = (int)(((long long)slot * N) >> 3);
  const int hi = (int)(((long long)(slot + 1) * N) >> 3);
  const int stride = (gridDim.x >> 3) * blockDim.x;
  for (int e = (blockIdx.x >> 3) * blockDim.x + threadIdx.x; e < Etot; e += stride){
    int d = (e < Eg) ? edst[e] : (e - Eg);
    if (d >= lo && d < hi) atomicAdd(&deg[d], 1);
  }
}

__global__ void __launch_bounds__(256) scatter_k(const int* __restrict__ esrc, const int* __restrict__ edst,
                                                 int* __restrict__ cursor, int* __restrict__ csr_src,
                                                 int Eg, int Etot, int N){
  const int slot = blockIdx.x & 7;
  const int lo = (int)(((long long)slot * N) >> 3);
  const int hi = (int)(((long long)(slot + 1) * N) >> 3);
  const int stride = (gridDim.x >> 3) * blockDim.x;
  for (int e = (blockIdx.x >> 3) * blockDim.x + threadIdx.x; e < Etot; e += stride){
    int s, d;
    if (e < Eg){ d = edst[e]; if (d < lo || d >= hi) continue; s = esrc[e]; }
    else { s = d = e - Eg; if (d < lo || d >= hi) continue; }
    int pos = atomicAdd(&cursor[d], 1);
    csr_src[pos] = s;
  }
}

// A: per-block sums (2048 elems / 256-thread block)
__global__ void __launch_bounds__(256) scan_part_k(const int* __restrict__ deg,
                                                   int* __restrict__ bsum, int N){
  __shared__ int red[256];
  const int t = threadIdx.x;
  const int base = blockIdx.x * 2048;
  int sum = 0;
  #pragma unroll
  for (int i = 0; i < 8; ++i){
    int idx = base + t + i * 256;
    if (idx < N) sum += deg[idx];
  }
  red[t] = sum; __syncthreads();
  #pragma unroll
  for (int d = 128; d; d >>= 1){
    if (t < d) red[t] += red[t + d];
    __syncthreads();
  }
  if (t == 0) bsum[blockIdx.x] = red[0];
}

// B: one wave scans the block sums (nb <= 64)
__global__ void scan_tops_k(const int* __restrict__ bsum, int* __restrict__ boff,
                            int* __restrict__ row, int nb, int N){
  int t = threadIdx.x;
  int v = (t < nb) ? bsum[t] : 0;
  int orig = v;
  #pragma unroll
  for (int off = 1; off < 64; off <<= 1){
    int u = __shfl_up(v, off, 64);
    if (t >= off) v += u;
  }
  if (t < nb) boff[t] = v - orig;
  if (t == nb - 1) row[N] = v;
}

// C: per-block local exclusive scan + global offset, write row & cursor
__global__ void __launch_bounds__(256) scan_write_k(const int* __restrict__ deg,
                                                    const int* __restrict__ boff,
                                                    int* __restrict__ row, int* __restrict__ cursor, int N){
  __shared__ int sdeg[2048];
  __shared__ int tsum[256];
  const int t = threadIdx.x;
  const int base = blockIdx.x * 2048;
  for (int i = t; i < 2048; i += 256){
    int idx = base + i;
    sdeg[i] = (idx < N) ? deg[idx] : 0;
  }
  __syncthreads();
  const int off = t * 8;
  int sum = 0;
  #pragma unroll
  for (int i = 0; i < 8; ++i) sum += sdeg[off + i];
  tsum[t] = sum; __syncthreads();
  for (int d = 1; d < 256; d <<= 1){
    int v = (t >= d) ? tsum[t - d] : 0;
    __syncthreads();
    tsum[t] += v;
    __syncthreads();
  }
  int run = boff[blockIdx.x] + ((t == 0) ? 0 : tsum[t - 1]);
  #pragma unroll
  for (int i = 0; i < 8; ++i){
    int idx = base + off + i;
    if (idx < N){ row[idx] = run; cursor[idx] = run; run += sdeg[off + i]; }
  }
}

// ---------------- layer 1 (Fin = 1, rank-1) ----------------
__global__ void dots1_k(const float* __restrict__ W1, const float* __restrict__ a_s,
                        const float* __restrict__ a_d, float* __restrict__ dAdD){
  int t = threadIdx.x;
  float ps = W1[t] * a_s[t];
  float pd = W1[t] * a_d[t];
  #pragma unroll
  for (int off = 16; off; off >>= 1){
    ps += __shfl_xor(ps, off, 32);
    pd += __shfl_xor(pd, off, 32);
  }
  if ((t & 31) == 0){ dAdD[t >> 5] = ps; dAdD[4 + (t >> 5)] = pd; }
}

// layer-1 softmax scalars only: r4[n] = (t_h/s_h for h=0..3). 8 lanes/node.
__global__ void __launch_bounds__(256) r1_k(const int* __restrict__ row, const int* __restrict__ csr_src,
                                            const float* __restrict__ x, const float* __restrict__ dAdD,
                                            float4* __restrict__ r4, int N){
  int node = blockIdx.x * 32 + (threadIdx.x >> 3);
  if (node >= N) return;
  const int q = threadIdx.x & 7;
  const int start = row[node], end = row[node + 1];
  const float xd = x[node];
  float dA0 = dAdD[0], dA1 = dAdD[1], dA2 = dAdD[2], dA3 = dAdD[3];
  float e0d = xd * dAdD[4], e1d = xd * dAdD[5], e2d = xd * dAdD[6], e3d = xd * dAdD[7];

  float s0 = 0.f, s1 = 0.f, s2 = 0.f, s3 = 0.f;
  float t0 = 0.f, t1 = 0.f, t2 = 0.f, t3 = 0.f;
  for (int i = start + q; i < end; i += 8){
    float xs = x[csr_src[i]];
    float p0 = __expf(leaky(xs * dA0 + e0d));
    float p1 = __expf(leaky(xs * dA1 + e1d));
    float p2 = __expf(leaky(xs * dA2 + e2d));
    float p3 = __expf(leaky(xs * dA3 + e3d));
    s0 += p0; s1 += p1; s2 += p2; s3 += p3;
    t0 += p0 * xs; t1 += p1 * xs; t2 += p2 * xs; t3 += p3 * xs;
  }
  #pragma unroll
  for (int off = 4; off; off >>= 1){
    s0 += __shfl_xor(s0, off, 8); t0 += __shfl_xor(t0, off, 8);
    s1 += __shfl_xor(s1, off, 8); t1 += __shfl_xor(t1, off, 8);
    s2 += __shfl_xor(s2, off, 8); t2 += __shfl_xor(t2, off, 8);
    s3 += __shfl_xor(s3, off, 8); t3 += __shfl_xor(t3, off, 8);
  }
  if (q == 0) r4[node] = make_float4(t0 / s0, t1 / s1, t2 / s2, t3 / s3);
}

// ---------------- layer 2 dense: h = act1(Nx128) * W2(128x128) ----------------
// act1 reconstructed in LDS (conflict-free: lanes span 64 nodes for fixed channel).
// W2 staged fp16 (1 b128 LDS read per k instead of 2). h out fp16 head-major.
__global__ void __launch_bounds__(256) gemm2_k(const float4* __restrict__ r4,
                                               const float* __restrict__ W1f, const float* __restrict__ b1f,
                                               const float* __restrict__ W,
                                               const float* __restrict__ a_s, const float* __restrict__ a_d,
                                               _Float16* __restrict__ hh, float* __restrict__ as_, float* __restrict__ ad_,
                                               int N){
  __shared__ float sA[128][68];        // [k][row] act1 tile, 34.8 KB
  __shared__ _Float16 sW[2][16][128];  // fp16 W tiles, 8 KB
  const int t = threadIdx.x;
  const int n0 = blockIdx.x * 64;
  const int tx = t & 15, ty = t >> 4;
  const int c0 = tx * 8, r0 = ty * 4;

  const int wk = t >> 5;         // 0..7: W k row
  const int wq = t & 31;         // W col-quad

  float4 rw0, rw1;
  auto gloadW = [&](int k0){
    rw0 = *(const float4*)&W[(size_t)(k0 + wk) * 128 + wq * 4];
    rw1 = *(const float4*)&W[(size_t)(k0 + wk + 8) * 128 + wq * 4];
  };
  auto sstoreW = [&](int buf){
    hv4 a = {(_Float16)rw0.x, (_Float16)rw0.y, (_Float16)rw0.z, (_Float16)rw0.w};
    hv4 b = {(_Float16)rw1.x, (_Float16)rw1.y, (_Float16)rw1.z, (_Float16)rw1.w};
    *(hv4*)&sW[buf][wk][wq * 4]     = a;
    *(hv4*)&sW[buf][wk + 8][wq * 4] = b;
  };

  // stage act1 tile, conflict-free: lane nl = t&63 (node), q = t>>6 (head, wave-uniform)
  {
    const int nl = t & 63, q = t >> 6;
    const int gn = n0 + nl;
    float r = 0.f;
    const bool valid = (gn < N);
    if (valid){
      float4 rv = r4[gn];
      r = (q == 0) ? rv.x : (q == 1) ? rv.y : (q == 2) ? rv.z : rv.w;
    }
    #pragma unroll
    for (int j = 0; j < 32; ++j){
      const int c = q * 32 + j;          // wave-uniform -> scalar W1/b1 loads
      float v = W1f[c] * r + b1f[c];
      v = eluf_fast(v);
      sA[c][nl] = valid ? v : 0.f;
    }
  }

  float acc[4][8];
  #pragma unroll
  for (int r = 0; r < 4; ++r)
    #pragma unroll
    for (int c = 0; c < 8; ++c) acc[r][c] = 0.f;

  gloadW(0); sstoreW(0); __syncthreads();

  #pragma unroll 1
  for (int tile = 0; tile < 8; ++tile){
    const int buf = tile & 1;
    if (tile < 7) gloadW((tile + 1) * 16);
    #pragma unroll
    for (int k = 0; k < 16; ++k){
      float4 aa = *(const float4*)&sA[tile * 16 + k][r0];
      hv8 wh = *(const hv8*)&sW[buf][k][c0];
      float av[4] = {aa.x, aa.y, aa.z, aa.w};
      float wv[8];
      #pragma unroll
      for (int c = 0; c < 8; ++c) wv[c] = (float)wh[c];
      #pragma unroll
      for (int r = 0; r < 4; ++r)
        #pragma unroll
        for (int c = 0; c < 8; ++c) acc[r][c] += av[r] * wv[c];
    }
    if (tile < 7){ sstoreW(1 - buf); __syncthreads(); }
  }

  float asv[8], adv[8];
  #pragma unroll
  for (int c = 0; c < 8; ++c){ asv[c] = a_s[c0 + c]; adv[c] = a_d[c0 + c]; }

  const int hd  = tx >> 2;            // head of this column group
  const int off = (tx & 3) * 8;       // channel offset within head

  #pragma unroll
  for (int r = 0; r < 4; ++r){
    int n = n0 + r0 + r;
    if (n >= N) continue;
    hv8 hv;
    #pragma unroll
    for (int c = 0; c < 8; ++c) hv[c] = (_Float16)acc[r][c];
    *(hv8*)&hh[((size_t)hd * N + n) * 32 + off] = hv;
    float ps = 0.f, pd = 0.f;
    #pragma unroll
    for (int c = 0; c < 8; ++c){ ps += acc[r][c] * asv[c]; pd += acc[r][c] * adv[c]; }
    ps += __shfl_xor(ps, 1); ps += __shfl_xor(ps, 2);
    pd += __shfl_xor(pd, 1); pd += __shfl_xor(pd, 2);
    if ((tx & 3) == 0){
      as_[(size_t)hd * N + n] = ps;   // head-major
      ad_[(size_t)hd * N + n] = pd;
    }
  }
}

// ---------------- per-node aggregate, layer 2: HEAD-SPLIT + XCD-pinned, fp16 h ----------------
template<bool DO_ELU>
__global__ void __launch_bounds__(256) node_aggr2_k(const int* __restrict__ row, const int* __restrict__ csr_src,
                                                    const float* __restrict__ as_, const float* __restrict__ ad_,
                                                    const _Float16* __restrict__ hh, const float4* __restrict__ bias4,
                                                    float4* __restrict__ out4, int N){
  const int slot   = blockIdx.x & 7;
  const int chunk  = blockIdx.x >> 3;
  const int head   = slot >> 1;
  const int parity = slot & 1;
  const int t  = threadIdx.x;
  const int nl = t >> 3;          // node slot 0..31
  const int q  = t & 7;           // lane within head
  const int node = chunk * 64 + parity * 32 + nl;
  if (node >= N) return;
  const int start = row[node], end = row[node + 1];
  const float* __restrict__ ash = as_ + (size_t)head * N;
  const _Float16* __restrict__ hhh = hh + (size_t)head * N * 32 + q * 4;
  const float adv = ad_[(size_t)head * N + node];

  float s = 0.f;
  float4 acc = make_float4(0.f, 0.f, 0.f, 0.f);
  int i = start;

  int pre = (4 - (start & 3)) & 3;
  if (pre > end - start) pre = end - start;
  for (int k = 0; k < pre; ++k, ++i){
    int src = csr_src[i];
    float p = __expf(leaky(ash[src] + adv));
    hv4 hv = *(const hv4*)&hhh[(size_t)src * 32];
    s += p;
    acc.x += (float)hv.x*p; acc.y += (float)hv.y*p; acc.z += (float)hv.z*p; acc.w += (float)hv.w*p;
  }
  for (; i + 4 <= end; i += 4){
    int4 ia = *(const int4*)&csr_src[i];
    float a0 = ash[ia.x], a1 = ash[ia.y], a2 = ash[ia.z], a3 = ash[ia.w];
    hv4 h0 = *(const hv4*)&hhh[(size_t)ia.x * 32];
    hv4 h1 = *(const hv4*)&hhh[(size_t)ia.y * 32];
    hv4 h2 = *(const hv4*)&hhh[(size_t)ia.z * 32];
    hv4 h3 = *(const hv4*)&hhh[(size_t)ia.w * 32];
    float p0 = __expf(leaky(a0 + adv));
    float p1 = __expf(leaky(a1 + adv));
    float p2 = __expf(leaky(a2 + adv));
    float p3 = __expf(leaky(a3 + adv));
    s += (p0 + p1) + (p2 + p3);
    acc.x += (float)h0.x*p0 + (float)h1.x*p1 + (float)h2.x*p2 + (float)h3.x*p3;
    acc.y += (float)h0.y*p0 + (float)h1.y*p1 + (float)h2.y*p2 + (float)h3.y*p3;
    acc.z += (float)h0.z*p0 + (float)h1.z*p1 + (float)h2.z*p2 + (float)h3.z*p3;
    acc.w += (float)h0.w*p0 + (float)h1.w*p1 + (float)h2.w*p2 + (float)h3.w*p3;
  }
  for (; i < end; ++i){
    int src = csr_src[i];
    float p = __expf(leaky(ash[src] + adv));
    hv4 hv = *(const hv4*)&hhh[(size_t)src * 32];
    s += p;
    acc.x += (float)hv.x*p; acc.y += (float)hv.y*p; acc.z += (float)hv.z*p; acc.w += (float)hv.w*p;
  }

  float inv = 1.f / s;
  const int cix = head * 8 + q;
  float4 b = bias4[cix];
  float4 v;
  v.x = acc.x * inv + b.x;
  v.y = acc.y * inv + b.y;
  v.z = acc.z * inv + b.z;
  v.w = acc.w * inv + b.w;
  if (DO_ELU){
    v.x = eluf(v.x); v.y = eluf(v.y); v.z = eluf(v.z); v.w = eluf(v.w);
  }
  out4[(size_t)node * 32 + cix] = v;
}

// ---------------- layer 3 ----------------
__global__ void __launch_bounds__(256) transform3_k(const float* __restrict__ A, const float* __restrict__ W3,
                                                    const float* __restrict__ a_s3, const float* __restrict__ a_d3,
                                                    float* __restrict__ h3, float* __restrict__ as_, float* __restrict__ ad_,
                                                    int N){
  int node = blockIdx.x * 8 + (threadIdx.x >> 5);
  if (node >= N) return;
  int j = threadIdx.x & 31;
  float4 a = ((const float4*)A)[(size_t)node * 32 + j];
  float4 w = ((const float4*)W3)[j];
  float acc = a.x * w.x + a.y * w.y + a.z * w.z + a.w * w.w;
  #pragma unroll
  for (int off = 16; off; off >>= 1) acc += __shfl_xor(acc, off, 32);
  if (j == 0){
    h3[node]  = acc;
    as_[node] = acc * a_s3[0];
    ad_[node] = acc * a_d3[0];
  }
}

// 8 lanes per node (avg degree 17)
__global__ void __launch_bounds__(256) node_aggr3_k(const int* __restrict__ row, const int* __restrict__ csr_src,
                                                    const float* __restrict__ as_, const float* __restrict__ ad_,
                                                    const float* __restrict__ h3, const float* __restrict__ b3,
                                                    float* __restrict__ out, int N){
  int node = blockIdx.x * 32 + (threadIdx.x >> 3);
  if (node >= N) return;
  int q = threadIdx.x & 7;
  int start = row[node], end = row[node + 1];
  float adv = ad_[node];
  float s = 0.f, acc = 0.f;
  for (int i = start + q; i < end; i += 8){
    int src = csr_src[i];
    float p = __expf(leaky(as_[src] + adv));
    s += p; acc += h3[src] * p;
  }
  #pragma unroll
  for (int off = 4; off; off >>= 1){
    s += __shfl_xor(s, off, 8);
    acc += __shfl_xor(acc, off, 8);
  }
  if (q == 0) out[node] = acc / s + b3[0];
}

// ---------------- launch ----------------
extern "C" void kernel_launch(void* const* d_in, const int* in_sizes, int n_in,
                              void* d_out, int out_size, void* d_ws, size_t ws_size,
                              hipStream_t stream){
  const float* x   = (const float*)d_in[0];
  const int*   ei  = (const int*)  d_in[1];
  const float* W1  = (const float*)d_in[2];
  const float* as1 = (const float*)d_in[3];
  const float* ad1 = (const float*)d_in[4];
  const float* b1  = (const float*)d_in[5];
  const float* W2  = (const float*)d_in[6];
  const float* as2 = (const float*)d_in[7];
  const float* ad2 = (const float*)d_in[8];
  const float* b2  = (const float*)d_in[9];
  const float* W3  = (const float*)d_in[10];
  const float* as3 = (const float*)d_in[11];
  const float* ad3 = (const float*)d_in[12];
  const float* b3  = (const float*)d_in[13];

  const int N    = in_sizes[0];       // IN_C = 1
  const int Eg   = in_sizes[1] / 2;
  const int Etot = Eg + N;
  const int* esrc = ei;
  const int* edst = ei + Eg;

  char* w = (char*)d_ws;
  auto carve = [&](size_t bytes)->char*{
    char* p = w; w += (bytes + 15) & ~size_t(15); return p;
  };
  _Float16* hbuf = (_Float16*)carve((size_t)N * 128 * 2);  // fp16 head-major [4][N][32]
  float* actA   = (float*)carve((size_t)N * 128 * 4);
  float* r4b    = (float*)carve((size_t)N * 4 * 4);
  float* asb    = (float*)carve((size_t)N * 4 * 4);   // head-major [4][N]
  float* adb    = (float*)carve((size_t)N * 4 * 4);   // head-major [4][N]
  float* h3b    = (float*)carve((size_t)N * 4);
  float* as3b   = (float*)carve((size_t)N * 4);
  float* ad3b   = (float*)carve((size_t)N * 4);
  int*   deg    = (int*)  carve((size_t)N * 4);
  int*   rowp   = (int*)  carve((size_t)(N + 1) * 4);
  int*   cursor = (int*)  carve((size_t)N * 4);
  int*   csr_src= (int*)  carve((size_t)Etot * 4);
  float* dAdD   = (float*)carve(8 * 4);
  int*   bsum   = (int*)  carve(64 * 4);
  int*   boff   = (int*)  carve(64 * 4);

  const int B = 256;
  auto cdiv = [](int a, int b){ return (a + b - 1) / b; };
  const int nb = cdiv(N, 2048);   // 25 for N=50000 (must be <= 64)

  // ---- CSR build (shared by all 3 layers) ----
  hipMemsetAsync(deg, 0, (size_t)N * 4, stream);
  hist_k<<<128 * 8, B, 0, stream>>>(edst, deg, Eg, Etot, N);
  scan_part_k<<<nb, B, 0, stream>>>(deg, bsum, N);
  scan_tops_k<<<1, 64, 0, stream>>>(bsum, boff, rowp, nb, N);
  scan_write_k<<<nb, B, 0, stream>>>(deg, boff, rowp, cursor, N);
  scatter_k<<<128 * 8, B, 0, stream>>>(esrc, edst, cursor, csr_src, Eg, Etot, N);

  // ---- layer 1 (rank-1: only softmax scalars r) ----
  dots1_k<<<1, 128, 0, stream>>>(W1, as1, ad1, dAdD);
  r1_k<<<cdiv(N, 32), B, 0, stream>>>(rowp, csr_src, x, dAdD, (float4*)r4b, N);

  // ---- layer 2 (act1 reconstructed in LDS; h fp16 head-major) ----
  gemm2_k<<<cdiv(N, 64), B, 0, stream>>>((const float4*)r4b, W1, b1,
                                         W2, as2, ad2, hbuf, asb, adb, N);
  node_aggr2_k<true><<<cdiv(N, 64) * 8, B, 0, stream>>>(rowp, csr_src, asb, adb,
                                                        hbuf, (const float4*)b2,
                                                        (float4*)actA, N);

  // ---- layer 3 (H=1, C=1) ----
  transform3_k<<<cdiv(N, 8), B, 0, stream>>>(actA, W3, as3, ad3, h3b, as3b, ad3b, N);
  node_aggr3_k<<<cdiv(N, 32), B, 0, stream>>>(rowp, csr_src, as3b, ad3b, h3b, b3, (float*)d_out, N);
}

// Round 14
// 280.701 us; speedup vs baseline: 1.4368x; 1.0187x over previous
//
#include <hip/hip_runtime.h>
#include <math.h>

#define NEG_SLOPE 0.2f

typedef _Float16 hv4 __attribute__((ext_vector_type(4)));
typedef _Float16 hv8 __attribute__((ext_vector_type(8)));

static __device__ __forceinline__ float leaky(float v){ return v > 0.f ? v : NEG_SLOPE * v; }
static __device__ __forceinline__ float eluf(float v){ return v > 0.f ? v : expm1f(v); }
static __device__ __forceinline__ float eluf_fast(float v){ return v > 0.f ? v : __expf(v) - 1.f; }

// ---------------- CSR build (XCD-range-partitioned) ----------------
__global__ void __launch_bounds__(256) hist_k(const int* __restrict__ edst, int* __restrict__ deg,
                                              int Eg, int Etot, int N){
  const int slot = blockIdx.x & 7;
  const int lo = (int)(((long long)slot * N) >> 3);
  const int hi = (int)(((long long)(slot + 1) * N) >> 3);
  const int stride = (gridDim.x >> 3) * blockDim.x;
  for (int e = (blockIdx.x >> 3) * blockDim.x + threadIdx.x; e < Etot; e += stride){
    int d = (e < Eg) ? edst[e] : (e - Eg);
    if (d >= lo && d < hi) atomicAdd(&deg[d], 1);
  }
}

__global__ void __launch_bounds__(256) scatter_k(const int* __restrict__ esrc, const int* __restrict__ edst,
                                                 int* __restrict__ cursor, int* __restrict__ csr_src,
                                                 int Eg, int Etot, int N){
  const int slot = blockIdx.x & 7;
  const int lo = (int)(((long long)slot * N) >> 3);
  const int hi = (int)(((long long)(slot + 1) * N) >> 3);
  const int stride = (gridDim.x >> 3) * blockDim.x;
  for (int e = (blockIdx.x >> 3) * blockDim.x + threadIdx.x; e < Etot; e += stride){
    int s, d;
    if (e < Eg){ d = edst[e]; if (d < lo || d >= hi) continue; s = esrc[e]; }
    else { s = d = e - Eg; if (d < lo || d >= hi) continue; }
    int pos = atomicAdd(&cursor[d], 1);
    csr_src[pos] = s;
  }
}

// A: per-block sums (2048 elems / 256-thread block)
__global__ void __launch_bounds__(256) scan_part_k(const int* __restrict__ deg,
                                                   int* __restrict__ bsum, int N){
  __shared__ int red[256];
  const int t = threadIdx.x;
  const int base = blockIdx.x * 2048;
  int sum = 0;
  #pragma unroll
  for (int i = 0; i < 8; ++i){
    int idx = base + t + i * 256;
    if (idx < N) sum += deg[idx];
  }
  red[t] = sum; __syncthreads();
  #pragma unroll
  for (int d = 128; d; d >>= 1){
    if (t < d) red[t] += red[t + d];
    __syncthreads();
  }
  if (t == 0) bsum[blockIdx.x] = red[0];
}

// B: one wave scans the block sums (nb <= 64)
__global__ void scan_tops_k(const int* __restrict__ bsum, int* __restrict__ boff,
                            int* __restrict__ row, int nb, int N){
  int t = threadIdx.x;
  int v = (t < nb) ? bsum[t] : 0;
  int orig = v;
  #pragma unroll
  for (int off = 1; off < 64; off <<= 1){
    int u = __shfl_up(v, off, 64);
    if (t >= off) v += u;
  }
  if (t < nb) boff[t] = v - orig;
  if (t == nb - 1) row[N] = v;
}

// C: per-block local exclusive scan + global offset, write row & cursor
__global__ void __launch_bounds__(256) scan_write_k(const int* __restrict__ deg,
                                                    const int* __restrict__ boff,
                                                    int* __restrict__ row, int* __restrict__ cursor, int N){
  __shared__ int sdeg[2048];
  __shared__ int tsum[256];
  const int t = threadIdx.x;
  const int base = blockIdx.x * 2048;
  for (int i = t; i < 2048; i += 256){
    int idx = base + i;
    sdeg[i] = (idx < N) ? deg[idx] : 0;
  }
  __syncthreads();
  const int off = t * 8;
  int sum = 0;
  #pragma unroll
  for (int i = 0; i < 8; ++i) sum += sdeg[off + i];
  tsum[t] = sum; __syncthreads();
  for (int d = 1; d < 256; d <<= 1){
    int v = (t >= d) ? tsum[t - d] : 0;
    __syncthreads();
    tsum[t] += v;
    __syncthreads();
  }
  int run = boff[blockIdx.x] + ((t == 0) ? 0 : tsum[t - 1]);
  #pragma unroll
  for (int i = 0; i < 8; ++i){
    int idx = base + off + i;
    if (idx < N){ row[idx] = run; cursor[idx] = run; run += sdeg[off + i]; }
  }
}

// ---------------- layer 1 (Fin = 1, rank-1) ----------------
__global__ void dots1_k(const float* __restrict__ W1, const float* __restrict__ a_s,
                        const float* __restrict__ a_d, float* __restrict__ dAdD){
  int t = threadIdx.x;
  float ps = W1[t] * a_s[t];
  float pd = W1[t] * a_d[t];
  #pragma unroll
  for (int off = 16; off; off >>= 1){
    ps += __shfl_xor(ps, off, 32);
    pd += __shfl_xor(pd, off, 32);
  }
  if ((t & 31) == 0){ dAdD[t >> 5] = ps; dAdD[4 + (t >> 5)] = pd; }
}

// layer-1 softmax scalars only: r4[n] = (t_h/s_h for h=0..3). 8 lanes/node.
__global__ void __launch_bounds__(256) r1_k(const int* __restrict__ row, const int* __restrict__ csr_src,
                                            const float* __restrict__ x, const float* __restrict__ dAdD,
                                            float4* __restrict__ r4, int N){
  int node = blockIdx.x * 32 + (threadIdx.x >> 3);
  if (node >= N) return;
  const int q = threadIdx.x & 7;
  const int start = row[node], end = row[node + 1];
  const float xd = x[node];
  float dA0 = dAdD[0], dA1 = dAdD[1], dA2 = dAdD[2], dA3 = dAdD[3];
  float e0d = xd * dAdD[4], e1d = xd * dAdD[5], e2d = xd * dAdD[6], e3d = xd * dAdD[7];

  float s0 = 0.f, s1 = 0.f, s2 = 0.f, s3 = 0.f;
  float t0 = 0.f, t1 = 0.f, t2 = 0.f, t3 = 0.f;
  for (int i = start + q; i < end; i += 8){
    float xs = x[csr_src[i]];
    float p0 = __expf(leaky(xs * dA0 + e0d));
    float p1 = __expf(leaky(xs * dA1 + e1d));
    float p2 = __expf(leaky(xs * dA2 + e2d));
    float p3 = __expf(leaky(xs * dA3 + e3d));
    s0 += p0; s1 += p1; s2 += p2; s3 += p3;
    t0 += p0 * xs; t1 += p1 * xs; t2 += p2 * xs; t3 += p3 * xs;
  }
  #pragma unroll
  for (int off = 4; off; off >>= 1){
    s0 += __shfl_xor(s0, off, 8); t0 += __shfl_xor(t0, off, 8);
    s1 += __shfl_xor(s1, off, 8); t1 += __shfl_xor(t1, off, 8);
    s2 += __shfl_xor(s2, off, 8); t2 += __shfl_xor(t2, off, 8);
    s3 += __shfl_xor(s3, off, 8); t3 += __shfl_xor(t3, off, 8);
  }
  if (q == 0) r4[node] = make_float4(t0 / s0, t1 / s1, t2 / s2, t3 / s3);
}

// ---------------- layer 2 dense: h = act1(Nx128) * W2(128x128) ----------------
__global__ void __launch_bounds__(256) gemm2_k(const float4* __restrict__ r4,
                                               const float* __restrict__ W1f, const float* __restrict__ b1f,
                                               const float* __restrict__ W,
                                               const float* __restrict__ a_s, const float* __restrict__ a_d,
                                               _Float16* __restrict__ hh, float* __restrict__ as_, float* __restrict__ ad_,
                                               int N){
  __shared__ float sA[128][68];        // [k][row] act1 tile, 34.8 KB
  __shared__ _Float16 sW[2][16][128];  // fp16 W tiles, 8 KB
  const int t = threadIdx.x;
  const int n0 = blockIdx.x * 64;
  const int tx = t & 15, ty = t >> 4;
  const int c0 = tx * 8, r0 = ty * 4;

  const int wk = t >> 5;         // 0..7: W k row
  const int wq = t & 31;         // W col-quad

  float4 rw0, rw1;
  auto gloadW = [&](int k0){
    rw0 = *(const float4*)&W[(size_t)(k0 + wk) * 128 + wq * 4];
    rw1 = *(const float4*)&W[(size_t)(k0 + wk + 8) * 128 + wq * 4];
  };
  auto sstoreW = [&](int buf){
    hv4 a = {(_Float16)rw0.x, (_Float16)rw0.y, (_Float16)rw0.z, (_Float16)rw0.w};
    hv4 b = {(_Float16)rw1.x, (_Float16)rw1.y, (_Float16)rw1.z, (_Float16)rw1.w};
    *(hv4*)&sW[buf][wk][wq * 4]     = a;
    *(hv4*)&sW[buf][wk + 8][wq * 4] = b;
  };

  // stage act1 tile, conflict-free: lane nl = t&63 (node), q = t>>6 (head, wave-uniform)
  {
    const int nl = t & 63, q = t >> 6;
    const int gn = n0 + nl;
    float r = 0.f;
    const bool valid = (gn < N);
    if (valid){
      float4 rv = r4[gn];
      r = (q == 0) ? rv.x : (q == 1) ? rv.y : (q == 2) ? rv.z : rv.w;
    }
    #pragma unroll
    for (int j = 0; j < 32; ++j){
      const int c = q * 32 + j;          // wave-uniform -> scalar W1/b1 loads
      float v = W1f[c] * r + b1f[c];
      v = eluf_fast(v);
      sA[c][nl] = valid ? v : 0.f;
    }
  }

  float acc[4][8];
  #pragma unroll
  for (int r = 0; r < 4; ++r)
    #pragma unroll
    for (int c = 0; c < 8; ++c) acc[r][c] = 0.f;

  gloadW(0); sstoreW(0); __syncthreads();

  #pragma unroll 1
  for (int tile = 0; tile < 8; ++tile){
    const int buf = tile & 1;
    if (tile < 7) gloadW((tile + 1) * 16);
    #pragma unroll
    for (int k = 0; k < 16; ++k){
      float4 aa = *(const float4*)&sA[tile * 16 + k][r0];
      hv8 wh = *(const hv8*)&sW[buf][k][c0];
      float av[4] = {aa.x, aa.y, aa.z, aa.w};
      float wv[8];
      #pragma unroll
      for (int c = 0; c < 8; ++c) wv[c] = (float)wh[c];
      #pragma unroll
      for (int r = 0; r < 4; ++r)
        #pragma unroll
        for (int c = 0; c < 8; ++c) acc[r][c] += av[r] * wv[c];
    }
    if (tile < 7){ sstoreW(1 - buf); __syncthreads(); }
  }

  float asv[8], adv[8];
  #pragma unroll
  for (int c = 0; c < 8; ++c){ asv[c] = a_s[c0 + c]; adv[c] = a_d[c0 + c]; }

  const int hd  = tx >> 2;            // head of this column group
  const int off = (tx & 3) * 8;       // channel offset within head

  #pragma unroll
  for (int r = 0; r < 4; ++r){
    int n = n0 + r0 + r;
    if (n >= N) continue;
    hv8 hv;
    #pragma unroll
    for (int c = 0; c < 8; ++c) hv[c] = (_Float16)acc[r][c];
    *(hv8*)&hh[((size_t)hd * N + n) * 32 + off] = hv;
    float ps = 0.f, pd = 0.f;
    #pragma unroll
    for (int c = 0; c < 8; ++c){ ps += acc[r][c] * asv[c]; pd += acc[r][c] * adv[c]; }
    ps += __shfl_xor(ps, 1); ps += __shfl_xor(ps, 2);
    pd += __shfl_xor(pd, 1); pd += __shfl_xor(pd, 2);
    if ((tx & 3) == 0){
      as_[(size_t)hd * N + n] = ps;   // head-major
      ad_[(size_t)hd * N + n] = pd;
    }
  }
}

// ---- layer-2 aggregate + fused layer-3 transform ----
// Cooperative p: lane q computes exp for edge i+q, broadcast via shfl(width 8).
// Epilogue: act2-slice dotted with W3, shuffle-reduced, atomicAdd into h3[node].
__global__ void __launch_bounds__(256) node_aggr2_k(const int* __restrict__ row, const int* __restrict__ csr_src,
                                                    const float* __restrict__ as_, const float* __restrict__ ad_,
                                                    const _Float16* __restrict__ hh, const float4* __restrict__ bias4,
                                                    const float4* __restrict__ W3_4, float* __restrict__ h3, int N){
  const int slot   = blockIdx.x & 7;
  const int chunk  = blockIdx.x >> 3;
  const int head   = slot >> 1;
  const int parity = slot & 1;
  const int t  = threadIdx.x;
  const int nl = t >> 3;          // node slot 0..31
  const int q  = t & 7;           // lane within head
  const int node = chunk * 64 + parity * 32 + nl;
  if (node >= N) return;
  const int start = row[node], end = row[node + 1];
  const float* __restrict__ ash = as_ + (size_t)head * N;
  const _Float16* __restrict__ hhh = hh + (size_t)head * N * 32 + q * 4;
  const float adv = ad_[(size_t)head * N + node];

  float s = 0.f;
  float4 acc = make_float4(0.f, 0.f, 0.f, 0.f);

  for (int i = start; i < end; i += 8){
    int m = end - i; if (m > 8) m = 8;
    int src_q = 0; float pv = 0.f;
    if (q < m){
      src_q = csr_src[i + q];
      pv = __expf(leaky(ash[src_q] + adv));
    }
    s += pv;                        // lane-partial; reduced at the end
    #pragma unroll
    for (int j = 0; j < 8; ++j){
      int   srcj = __shfl(src_q, j, 8);
      float pj   = __shfl(pv, j, 8);
      if (j < m){
        hv4 hv = *(const hv4*)&hhh[(size_t)srcj * 32];
        acc.x += (float)hv.x * pj;
        acc.y += (float)hv.y * pj;
        acc.z += (float)hv.z * pj;
        acc.w += (float)hv.w * pj;
      }
    }
  }
  // reduce s over the 8-lane group
  #pragma unroll
  for (int off = 4; off; off >>= 1) s += __shfl_xor(s, off, 8);

  const float inv = 1.f / s;
  const int cix = head * 8 + q;
  float4 b = bias4[cix];
  float4 v;
  v.x = eluf(acc.x * inv + b.x);
  v.y = eluf(acc.y * inv + b.y);
  v.z = eluf(acc.z * inv + b.z);
  v.w = eluf(acc.w * inv + b.w);

  // fused layer-3 transform: partial = dot(act2 slice, W3 slice)
  float4 w3 = W3_4[cix];
  float part = v.x * w3.x + v.y * w3.y + v.z * w3.z + v.w * w3.w;
  #pragma unroll
  for (int off = 4; off; off >>= 1) part += __shfl_xor(part, off, 8);
  if (q == 0) unsafeAtomicAdd(&h3[node], part);
}

// layer-3 aggregate: e computed inline from h3 (as3 = a_s3*h3, ad3 = a_d3*h3). 8 lanes/node.
__global__ void __launch_bounds__(256) node_aggr3_k(const int* __restrict__ row, const int* __restrict__ csr_src,
                                                    const float* __restrict__ h3,
                                                    const float* __restrict__ a_s3, const float* __restrict__ a_d3,
                                                    const float* __restrict__ b3,
                                                    float* __restrict__ out, int N){
  int node = blockIdx.x * 32 + (threadIdx.x >> 3);
  if (node >= N) return;
  int q = threadIdx.x & 7;
  int start = row[node], end = row[node + 1];
  const float a_s3v = a_s3[0];
  const float adv = a_d3[0] * h3[node];
  float s = 0.f, acc = 0.f;
  for (int i = start + q; i < end; i += 8){
    int src = csr_src[i];
    float hv = h3[src];
    float p = __expf(leaky(a_s3v * hv + adv));
    s += p; acc += hv * p;
  }
  #pragma unroll
  for (int off = 4; off; off >>= 1){
    s += __shfl_xor(s, off, 8);
    acc += __shfl_xor(acc, off, 8);
  }
  if (q == 0) out[node] = acc / s + b3[0];
}

// ---------------- launch ----------------
extern "C" void kernel_launch(void* const* d_in, const int* in_sizes, int n_in,
                              void* d_out, int out_size, void* d_ws, size_t ws_size,
                              hipStream_t stream){
  const float* x   = (const float*)d_in[0];
  const int*   ei  = (const int*)  d_in[1];
  const float* W1  = (const float*)d_in[2];
  const float* as1 = (const float*)d_in[3];
  const float* ad1 = (const float*)d_in[4];
  const float* b1  = (const float*)d_in[5];
  const float* W2  = (const float*)d_in[6];
  const float* as2 = (const float*)d_in[7];
  const float* ad2 = (const float*)d_in[8];
  const float* b2  = (const float*)d_in[9];
  const float* W3  = (const float*)d_in[10];
  const float* as3 = (const float*)d_in[11];
  const float* ad3 = (const float*)d_in[12];
  const float* b3  = (const float*)d_in[13];

  const int N    = in_sizes[0];       // IN_C = 1
  const int Eg   = in_sizes[1] / 2;
  const int Etot = Eg + N;
  const int* esrc = ei;
  const int* edst = ei + Eg;

  char* w = (char*)d_ws;
  auto carve = [&](size_t bytes)->char*{
    char* p = w; w += (bytes + 15) & ~size_t(15); return p;
  };
  _Float16* hbuf = (_Float16*)carve((size_t)N * 128 * 2);  // fp16 head-major [4][N][32]
  float* r4b    = (float*)carve((size_t)N * 4 * 4);
  float* asb    = (float*)carve((size_t)N * 4 * 4);   // head-major [4][N]
  float* adb    = (float*)carve((size_t)N * 4 * 4);   // head-major [4][N]
  float* h3b    = (float*)carve((size_t)N * 4);
  int*   deg    = (int*)  carve((size_t)N * 4);
  int*   rowp   = (int*)  carve((size_t)(N + 1) * 4);
  int*   cursor = (int*)  carve((size_t)N * 4);
  int*   csr_src= (int*)  carve((size_t)Etot * 4);
  float* dAdD   = (float*)carve(8 * 4);
  int*   bsum   = (int*)  carve(64 * 4);
  int*   boff   = (int*)  carve(64 * 4);

  const int B = 256;
  auto cdiv = [](int a, int b){ return (a + b - 1) / b; };
  const int nb = cdiv(N, 2048);   // 25 for N=50000 (must be <= 64)

  // ---- CSR build (shared by all 3 layers) ----
  hipMemsetAsync(deg, 0, (size_t)N * 4, stream);
  hipMemsetAsync(h3b, 0, (size_t)N * 4, stream);
  hist_k<<<128 * 8, B, 0, stream>>>(edst, deg, Eg, Etot, N);
  scan_part_k<<<nb, B, 0, stream>>>(deg, bsum, N);
  scan_tops_k<<<1, 64, 0, stream>>>(bsum, boff, rowp, nb, N);
  scan_write_k<<<nb, B, 0, stream>>>(deg, boff, rowp, cursor, N);
  scatter_k<<<128 * 8, B, 0, stream>>>(esrc, edst, cursor, csr_src, Eg, Etot, N);

  // ---- layer 1 (rank-1: only softmax scalars r) ----
  dots1_k<<<1, 128, 0, stream>>>(W1, as1, ad1, dAdD);
  r1_k<<<cdiv(N, 32), B, 0, stream>>>(rowp, csr_src, x, dAdD, (float4*)r4b, N);

  // ---- layer 2 (act1 reconstructed in LDS; h fp16 head-major) ----
  gemm2_k<<<cdiv(N, 64), B, 0, stream>>>((const float4*)r4b, W1, b1,
                                         W2, as2, ad2, hbuf, asb, adb, N);
  // aggregate + fused layer-3 transform (writes h3 via atomics)
  node_aggr2_k<<<cdiv(N, 64) * 8, B, 0, stream>>>(rowp, csr_src, asb, adb,
                                                  hbuf, (const float4*)b2,
                                                  (const float4*)W3, h3b, N);

  // ---- layer 3 aggregate (H=1, C=1) ----
  node_aggr3_k<<<cdiv(N, 32), B, 0, stream>>>(rowp, csr_src, h3b, as3, ad3, b3, (float*)d_out, N);
}

// Round 15
// 275.373 us; speedup vs baseline: 1.4646x; 1.0193x over previous
//
#include <hip/hip_runtime.h>
#include <math.h>

#define NEG_SLOPE 0.2f

typedef _Float16 hv4 __attribute__((ext_vector_type(4)));
typedef _Float16 hv8 __attribute__((ext_vector_type(8)));

static __device__ __forceinline__ float leaky(float v){ return v > 0.f ? v : NEG_SLOPE * v; }
static __device__ __forceinline__ float eluf(float v){ return v > 0.f ? v : expm1f(v); }
static __device__ __forceinline__ float eluf_fast(float v){ return v > 0.f ? v : __expf(v) - 1.f; }

// ---------------- CSR build (XCD-range-partitioned) ----------------
__global__ void __launch_bounds__(256) hist_k(const int* __restrict__ edst, int* __restrict__ deg,
                                              int Eg, int Etot, int N){
  const int slot = blockIdx.x & 7;
  const int lo = (int)(((long long)slot * N) >> 3);
  const int hi = (int)(((long long)(slot + 1) * N) >> 3);
  const int stride = (gridDim.x >> 3) * blockDim.x;
  for (int e = (blockIdx.x >> 3) * blockDim.x + threadIdx.x; e < Etot; e += stride){
    int d = (e < Eg) ? edst[e] : (e - Eg);
    if (d >= lo && d < hi) atomicAdd(&deg[d], 1);
  }
}

__global__ void __launch_bounds__(256) scatter_k(const int* __restrict__ esrc, const int* __restrict__ edst,
                                                 int* __restrict__ cursor, int* __restrict__ csr_src,
                                                 int Eg, int Etot, int N){
  const int slot = blockIdx.x & 7;
  const int lo = (int)(((long long)slot * N) >> 3);
  const int hi = (int)(((long long)(slot + 1) * N) >> 3);
  const int stride = (gridDim.x >> 3) * blockDim.x;
  for (int e = (blockIdx.x >> 3) * blockDim.x + threadIdx.x; e < Etot; e += stride){
    int s, d;
    if (e < Eg){ d = edst[e]; if (d < lo || d >= hi) continue; s = esrc[e]; }
    else { s = d = e - Eg; if (d < lo || d >= hi) continue; }
    int pos = atomicAdd(&cursor[d], 1);
    csr_src[pos] = s;
  }
}

// A: per-block sums (2048 elems / 256-thread block)
__global__ void __launch_bounds__(256) scan_part_k(const int* __restrict__ deg,
                                                   int* __restrict__ bsum, int N){
  __shared__ int red[256];
  const int t = threadIdx.x;
  const int base = blockIdx.x * 2048;
  int sum = 0;
  #pragma unroll
  for (int i = 0; i < 8; ++i){
    int idx = base + t + i * 256;
    if (idx < N) sum += deg[idx];
  }
  red[t] = sum; __syncthreads();
  #pragma unroll
  for (int d = 128; d; d >>= 1){
    if (t < d) red[t] += red[t + d];
    __syncthreads();
  }
  if (t == 0) bsum[blockIdx.x] = red[0];
}

// B: one wave scans the block sums (nb <= 64)
__global__ void scan_tops_k(const int* __restrict__ bsum, int* __restrict__ boff,
                            int* __restrict__ row, int nb, int N){
  int t = threadIdx.x;
  int v = (t < nb) ? bsum[t] : 0;
  int orig = v;
  #pragma unroll
  for (int off = 1; off < 64; off <<= 1){
    int u = __shfl_up(v, off, 64);
    if (t >= off) v += u;
  }
  if (t < nb) boff[t] = v - orig;
  if (t == nb - 1) row[N] = v;
}

// C: per-block local exclusive scan + global offset, write row & cursor
__global__ void __launch_bounds__(256) scan_write_k(const int* __restrict__ deg,
                                                    const int* __restrict__ boff,
                                                    int* __restrict__ row, int* __restrict__ cursor, int N){
  __shared__ int sdeg[2048];
  __shared__ int tsum[256];
  const int t = threadIdx.x;
  const int base = blockIdx.x * 2048;
  for (int i = t; i < 2048; i += 256){
    int idx = base + i;
    sdeg[i] = (idx < N) ? deg[idx] : 0;
  }
  __syncthreads();
  const int off = t * 8;
  int sum = 0;
  #pragma unroll
  for (int i = 0; i < 8; ++i) sum += sdeg[off + i];
  tsum[t] = sum; __syncthreads();
  for (int d = 1; d < 256; d <<= 1){
    int v = (t >= d) ? tsum[t - d] : 0;
    __syncthreads();
    tsum[t] += v;
    __syncthreads();
  }
  int run = boff[blockIdx.x] + ((t == 0) ? 0 : tsum[t - 1]);
  #pragma unroll
  for (int i = 0; i < 8; ++i){
    int idx = base + off + i;
    if (idx < N){ row[idx] = run; cursor[idx] = run; run += sdeg[off + i]; }
  }
}

// ---------------- layer 1 (Fin = 1, rank-1) ----------------
__global__ void dots1_k(const float* __restrict__ W1, const float* __restrict__ a_s,
                        const float* __restrict__ a_d, float* __restrict__ dAdD){
  int t = threadIdx.x;
  float ps = W1[t] * a_s[t];
  float pd = W1[t] * a_d[t];
  #pragma unroll
  for (int off = 16; off; off >>= 1){
    ps += __shfl_xor(ps, off, 32);
    pd += __shfl_xor(pd, off, 32);
  }
  if ((t & 31) == 0){ dAdD[t >> 5] = ps; dAdD[4 + (t >> 5)] = pd; }
}

// layer-1 softmax scalars only: r4[n] = (t_h/s_h for h=0..3). 8 lanes/node.
__global__ void __launch_bounds__(256) r1_k(const int* __restrict__ row, const int* __restrict__ csr_src,
                                            const float* __restrict__ x, const float* __restrict__ dAdD,
                                            float4* __restrict__ r4, int N){
  int node = blockIdx.x * 32 + (threadIdx.x >> 3);
  if (node >= N) return;
  const int q = threadIdx.x & 7;
  const int start = row[node], end = row[node + 1];
  const float xd = x[node];
  float dA0 = dAdD[0], dA1 = dAdD[1], dA2 = dAdD[2], dA3 = dAdD[3];
  float e0d = xd * dAdD[4], e1d = xd * dAdD[5], e2d = xd * dAdD[6], e3d = xd * dAdD[7];

  float s0 = 0.f, s1 = 0.f, s2 = 0.f, s3 = 0.f;
  float t0 = 0.f, t1 = 0.f, t2 = 0.f, t3 = 0.f;
  for (int i = start + q; i < end; i += 8){
    float xs = x[csr_src[i]];
    float p0 = __expf(leaky(xs * dA0 + e0d));
    float p1 = __expf(leaky(xs * dA1 + e1d));
    float p2 = __expf(leaky(xs * dA2 + e2d));
    float p3 = __expf(leaky(xs * dA3 + e3d));
    s0 += p0; s1 += p1; s2 += p2; s3 += p3;
    t0 += p0 * xs; t1 += p1 * xs; t2 += p2 * xs; t3 += p3 * xs;
  }
  #pragma unroll
  for (int off = 4; off; off >>= 1){
    s0 += __shfl_xor(s0, off, 8); t0 += __shfl_xor(t0, off, 8);
    s1 += __shfl_xor(s1, off, 8); t1 += __shfl_xor(t1, off, 8);
    s2 += __shfl_xor(s2, off, 8); t2 += __shfl_xor(t2, off, 8);
    s3 += __shfl_xor(s3, off, 8); t3 += __shfl_xor(t3, off, 8);
  }
  if (q == 0) r4[node] = make_float4(t0 / s0, t1 / s1, t2 / s2, t3 / s3);
}

// ---------------- layer 2 dense: h = act1(Nx128) * W2(128x128) ----------------
__global__ void __launch_bounds__(256) gemm2_k(const float4* __restrict__ r4,
                                               const float* __restrict__ W1f, const float* __restrict__ b1f,
                                               const float* __restrict__ W,
                                               const float* __restrict__ a_s, const float* __restrict__ a_d,
                                               _Float16* __restrict__ hh, float* __restrict__ as_, float* __restrict__ ad_,
                                               int N){
  __shared__ float sA[128][68];        // [k][row] act1 tile, 34.8 KB
  __shared__ _Float16 sW[2][16][128];  // fp16 W tiles, 8 KB
  const int t = threadIdx.x;
  const int n0 = blockIdx.x * 64;
  const int tx = t & 15, ty = t >> 4;
  const int c0 = tx * 8, r0 = ty * 4;

  const int wk = t >> 5;         // 0..7: W k row
  const int wq = t & 31;         // W col-quad

  float4 rw0, rw1;
  auto gloadW = [&](int k0){
    rw0 = *(const float4*)&W[(size_t)(k0 + wk) * 128 + wq * 4];
    rw1 = *(const float4*)&W[(size_t)(k0 + wk + 8) * 128 + wq * 4];
  };
  auto sstoreW = [&](int buf){
    hv4 a = {(_Float16)rw0.x, (_Float16)rw0.y, (_Float16)rw0.z, (_Float16)rw0.w};
    hv4 b = {(_Float16)rw1.x, (_Float16)rw1.y, (_Float16)rw1.z, (_Float16)rw1.w};
    *(hv4*)&sW[buf][wk][wq * 4]     = a;
    *(hv4*)&sW[buf][wk + 8][wq * 4] = b;
  };

  // stage act1 tile, conflict-free: lane nl = t&63 (node), q = t>>6 (head, wave-uniform)
  {
    const int nl = t & 63, q = t >> 6;
    const int gn = n0 + nl;
    float r = 0.f;
    const bool valid = (gn < N);
    if (valid){
      float4 rv = r4[gn];
      r = (q == 0) ? rv.x : (q == 1) ? rv.y : (q == 2) ? rv.z : rv.w;
    }
    #pragma unroll
    for (int j = 0; j < 32; ++j){
      const int c = q * 32 + j;          // wave-uniform -> scalar W1/b1 loads
      float v = W1f[c] * r + b1f[c];
      v = eluf_fast(v);
      sA[c][nl] = valid ? v : 0.f;
    }
  }

  float acc[4][8];
  #pragma unroll
  for (int r = 0; r < 4; ++r)
    #pragma unroll
    for (int c = 0; c < 8; ++c) acc[r][c] = 0.f;

  gloadW(0); sstoreW(0); __syncthreads();

  #pragma unroll 1
  for (int tile = 0; tile < 8; ++tile){
    const int buf = tile & 1;
    if (tile < 7) gloadW((tile + 1) * 16);
    #pragma unroll
    for (int k = 0; k < 16; ++k){
      float4 aa = *(const float4*)&sA[tile * 16 + k][r0];
      hv8 wh = *(const hv8*)&sW[buf][k][c0];
      float av[4] = {aa.x, aa.y, aa.z, aa.w};
      float wv[8];
      #pragma unroll
      for (int c = 0; c < 8; ++c) wv[c] = (float)wh[c];
      #pragma unroll
      for (int r = 0; r < 4; ++r)
        #pragma unroll
        for (int c = 0; c < 8; ++c) acc[r][c] += av[r] * wv[c];
    }
    if (tile < 7){ sstoreW(1 - buf); __syncthreads(); }
  }

  float asv[8], adv[8];
  #pragma unroll
  for (int c = 0; c < 8; ++c){ asv[c] = a_s[c0 + c]; adv[c] = a_d[c0 + c]; }

  const int hd  = tx >> 2;            // head of this column group
  const int off = (tx & 3) * 8;       // channel offset within head

  #pragma unroll
  for (int r = 0; r < 4; ++r){
    int n = n0 + r0 + r;
    if (n >= N) continue;
    hv8 hv;
    #pragma unroll
    for (int c = 0; c < 8; ++c) hv[c] = (_Float16)acc[r][c];
    *(hv8*)&hh[((size_t)hd * N + n) * 32 + off] = hv;
    float ps = 0.f, pd = 0.f;
    #pragma unroll
    for (int c = 0; c < 8; ++c){ ps += acc[r][c] * asv[c]; pd += acc[r][c] * adv[c]; }
    ps += __shfl_xor(ps, 1); ps += __shfl_xor(ps, 2);
    pd += __shfl_xor(pd, 1); pd += __shfl_xor(pd, 2);
    if ((tx & 3) == 0){
      as_[(size_t)hd * N + n] = ps;   // head-major
      ad_[(size_t)hd * N + n] = pd;
    }
  }
}

// ---- layer-2 aggregate + fused layer-3 transform ----
// 4 lanes/node (lane q owns 8 channels = 16 B of the 64-B head row).
// Redundant exp across the 4 lanes -> s is lane-uniform, no reduce needed.
// 4-edge unroll: int4 idx load + 4 independent hv8 gathers in flight.
__global__ void __launch_bounds__(256) node_aggr2_k(const int* __restrict__ row, const int* __restrict__ csr_src,
                                                    const float* __restrict__ as_, const float* __restrict__ ad_,
                                                    const _Float16* __restrict__ hh, const float* __restrict__ b2,
                                                    const float* __restrict__ W3, float* __restrict__ h3, int N){
  const int slot   = blockIdx.x & 7;
  const int chunk  = blockIdx.x >> 3;
  const int head   = slot >> 1;
  const int parity = slot & 1;
  const int t  = threadIdx.x;
  const int nl = t >> 2;          // node slot 0..63
  const int q  = t & 3;           // lane within node
  const int node = chunk * 128 + parity * 64 + nl;
  if (node >= N) return;
  const int start = row[node], end = row[node + 1];
  const float* __restrict__ ash = as_ + (size_t)head * N;
  const _Float16* __restrict__ hhh = hh + (size_t)head * N * 32 + q * 8;
  const float adv = ad_[(size_t)head * N + node];

  float s = 0.f;
  float acc[8] = {0.f, 0.f, 0.f, 0.f, 0.f, 0.f, 0.f, 0.f};
  int i = start;

  // prologue: align i to a multiple of 4 (csr_src is 16B-aligned)
  int pre = (4 - (start & 3)) & 3;
  if (pre > end - start) pre = end - start;
  for (int k = 0; k < pre; ++k, ++i){
    int src = csr_src[i];
    float p = __expf(leaky(ash[src] + adv));
    hv8 hv = *(const hv8*)&hhh[(size_t)src * 32];
    s += p;
    #pragma unroll
    for (int c = 0; c < 8; ++c) acc[c] += (float)hv[c] * p;
  }
  // main: 4 edges/iter, batched gathers
  for (; i + 4 <= end; i += 4){
    int4 ia = *(const int4*)&csr_src[i];
    float a0 = ash[ia.x], a1 = ash[ia.y], a2 = ash[ia.z], a3 = ash[ia.w];
    hv8 h0 = *(const hv8*)&hhh[(size_t)ia.x * 32];
    hv8 h1 = *(const hv8*)&hhh[(size_t)ia.y * 32];
    hv8 h2 = *(const hv8*)&hhh[(size_t)ia.z * 32];
    hv8 h3v = *(const hv8*)&hhh[(size_t)ia.w * 32];
    float p0 = __expf(leaky(a0 + adv));
    float p1 = __expf(leaky(a1 + adv));
    float p2 = __expf(leaky(a2 + adv));
    float p3 = __expf(leaky(a3 + adv));
    s += (p0 + p1) + (p2 + p3);
    #pragma unroll
    for (int c = 0; c < 8; ++c)
      acc[c] += (float)h0[c]*p0 + (float)h1[c]*p1 + (float)h2[c]*p2 + (float)h3v[c]*p3;
  }
  // tail
  for (; i < end; ++i){
    int src = csr_src[i];
    float p = __expf(leaky(ash[src] + adv));
    hv8 hv = *(const hv8*)&hhh[(size_t)src * 32];
    s += p;
    #pragma unroll
    for (int c = 0; c < 8; ++c) acc[c] += (float)hv[c] * p;
  }

  const float inv = 1.f / s;
  const int c0 = head * 32 + q * 8;
  // act2 slice + fused layer-3 partial dot
  float part = 0.f;
  #pragma unroll
  for (int c = 0; c < 8; ++c){
    float v = eluf(acc[c] * inv + b2[c0 + c]);
    part += v * W3[c0 + c];
  }
  part += __shfl_xor(part, 1, 4);
  part += __shfl_xor(part, 2, 4);
  if (q == 0) unsafeAtomicAdd(&h3[node], part);
}

// layer-3 aggregate: e computed inline from h3 (as3 = a_s3*h3, ad3 = a_d3*h3). 8 lanes/node.
__global__ void __launch_bounds__(256) node_aggr3_k(const int* __restrict__ row, const int* __restrict__ csr_src,
                                                    const float* __restrict__ h3,
                                                    const float* __restrict__ a_s3, const float* __restrict__ a_d3,
                                                    const float* __restrict__ b3,
                                                    float* __restrict__ out, int N){
  int node = blockIdx.x * 32 + (threadIdx.x >> 3);
  if (node >= N) return;
  int q = threadIdx.x & 7;
  int start = row[node], end = row[node + 1];
  const float a_s3v = a_s3[0];
  const float adv = a_d3[0] * h3[node];
  float s = 0.f, acc = 0.f;
  for (int i = start + q; i < end; i += 8){
    int src = csr_src[i];
    float hv = h3[src];
    float p = __expf(leaky(a_s3v * hv + adv));
    s += p; acc += hv * p;
  }
  #pragma unroll
  for (int off = 4; off; off >>= 1){
    s += __shfl_xor(s, off, 8);
    acc += __shfl_xor(acc, off, 8);
  }
  if (q == 0) out[node] = acc / s + b3[0];
}

// ---------------- launch ----------------
extern "C" void kernel_launch(void* const* d_in, const int* in_sizes, int n_in,
                              void* d_out, int out_size, void* d_ws, size_t ws_size,
                              hipStream_t stream){
  const float* x   = (const float*)d_in[0];
  const int*   ei  = (const int*)  d_in[1];
  const float* W1  = (const float*)d_in[2];
  const float* as1 = (const float*)d_in[3];
  const float* ad1 = (const float*)d_in[4];
  const float* b1  = (const float*)d_in[5];
  const float* W2  = (const float*)d_in[6];
  const float* as2 = (const float*)d_in[7];
  const float* ad2 = (const float*)d_in[8];
  const float* b2  = (const float*)d_in[9];
  const float* W3  = (const float*)d_in[10];
  const float* as3 = (const float*)d_in[11];
  const float* ad3 = (const float*)d_in[12];
  const float* b3  = (const float*)d_in[13];

  const int N    = in_sizes[0];       // IN_C = 1
  const int Eg   = in_sizes[1] / 2;
  const int Etot = Eg + N;
  const int* esrc = ei;
  const int* edst = ei + Eg;

  char* w = (char*)d_ws;
  auto carve = [&](size_t bytes)->char*{
    char* p = w; w += (bytes + 15) & ~size_t(15); return p;
  };
  _Float16* hbuf = (_Float16*)carve((size_t)N * 128 * 2);  // fp16 head-major [4][N][32]
  float* r4b    = (float*)carve((size_t)N * 4 * 4);
  float* asb    = (float*)carve((size_t)N * 4 * 4);   // head-major [4][N]
  float* adb    = (float*)carve((size_t)N * 4 * 4);   // head-major [4][N]
  float* h3b    = (float*)carve((size_t)N * 4);
  int*   deg    = (int*)  carve((size_t)N * 4);
  int*   rowp   = (int*)  carve((size_t)(N + 1) * 4);
  int*   cursor = (int*)  carve((size_t)N * 4);
  int*   csr_src= (int*)  carve((size_t)Etot * 4);
  float* dAdD   = (float*)carve(8 * 4);
  int*   bsum   = (int*)  carve(64 * 4);
  int*   boff   = (int*)  carve(64 * 4);

  const int B = 256;
  auto cdiv = [](int a, int b){ return (a + b - 1) / b; };
  const int nb = cdiv(N, 2048);   // 25 for N=50000 (must be <= 64)

  // ---- CSR build (shared by all 3 layers) ----
  hipMemsetAsync(deg, 0, (size_t)N * 4, stream);
  hipMemsetAsync(h3b, 0, (size_t)N * 4, stream);
  hist_k<<<128 * 8, B, 0, stream>>>(edst, deg, Eg, Etot, N);
  scan_part_k<<<nb, B, 0, stream>>>(deg, bsum, N);
  scan_tops_k<<<1, 64, 0, stream>>>(bsum, boff, rowp, nb, N);
  scan_write_k<<<nb, B, 0, stream>>>(deg, boff, rowp, cursor, N);
  scatter_k<<<128 * 8, B, 0, stream>>>(esrc, edst, cursor, csr_src, Eg, Etot, N);

  // ---- layer 1 (rank-1: only softmax scalars r) ----
  dots1_k<<<1, 128, 0, stream>>>(W1, as1, ad1, dAdD);
  r1_k<<<cdiv(N, 32), B, 0, stream>>>(rowp, csr_src, x, dAdD, (float4*)r4b, N);

  // ---- layer 2 (act1 reconstructed in LDS; h fp16 head-major) ----
  gemm2_k<<<cdiv(N, 64), B, 0, stream>>>((const float4*)r4b, W1, b1,
                                         W2, as2, ad2, hbuf, asb, adb, N);
  // aggregate + fused layer-3 transform (writes h3 via atomics)
  node_aggr2_k<<<cdiv(N, 128) * 8, B, 0, stream>>>(rowp, csr_src, asb, adb,
                                                   hbuf, b2, W3, h3b, N);

  // ---- layer 3 aggregate (H=1, C=1) ----
  node_aggr3_k<<<cdiv(N, 32), B, 0, stream>>>(rowp, csr_src, h3b, as3, ad3, b3, (float*)d_out, N);
}